// Round 1
// baseline (447.002 us; speedup 1.0000x reference)
//
#include <hip/hip_runtime.h>
#include <math.h>

#define B_ROWS 8192

// ---------------------------------------------------------------------------
// row_reduce: one block (256 thr) per row of X [rows, K]
//   mode 0: out[row] = rowsum / sqrt(rowsumsq)      (s = sum(xn))
//   mode 1: out[row] = sIn[row] / sqrt(rowsumsq)    (w = s / ||T_row||)
//   mode 2: out[row] = rowsum                       (rowsum of H)
// ---------------------------------------------------------------------------
__global__ __launch_bounds__(256) void row_reduce(
    const float* __restrict__ X, const float* __restrict__ sIn,
    float* __restrict__ outv, int K, int mode)
{
    const int row = blockIdx.x;
    const float* Xp = X + (size_t)row * K;
    const int tid = threadIdx.x;
    float sum = 0.f, sq = 0.f;
    for (int k = tid; k < K; k += 256) { float v = Xp[k]; sum += v; sq += v * v; }
    __shared__ float sSum[256], sSq[256];
    sSum[tid] = sum; sSq[tid] = sq;
    __syncthreads();
    for (int st = 128; st > 0; st >>= 1) {
        if (tid < st) { sSum[tid] += sSum[tid + st]; sSq[tid] += sSq[tid + st]; }
        __syncthreads();
    }
    if (tid == 0) {
        if (mode == 0)      outv[row] = sSum[0] / sqrtf(sSq[0]);
        else if (mode == 1) outv[row] = sIn[row] / sqrtf(sSq[0]);
        else                outv[row] = sSum[0];
    }
}

// ---------------------------------------------------------------------------
// zerov: zero n floats (score accumulator; d_ws is poisoned each call)
// ---------------------------------------------------------------------------
__global__ void zerov(float* __restrict__ p, int n)
{
    int i = blockIdx.x * blockDim.x + threadIdx.x;
    if (i < n) p[i] = 0.f;
}

// ---------------------------------------------------------------------------
// colscore: score[y] += sum_b T[b,y] * w[b], coalesced row-major reads.
// ysize divides 256 (256/128/64). Each block handles rowsPerBlock rows.
// ---------------------------------------------------------------------------
__global__ __launch_bounds__(256) void colscore(
    const float* __restrict__ T, const float* __restrict__ w,
    float* __restrict__ score, int ysize, int rowsPerBlock)
{
    const int tid = threadIdx.x;
    const int y = tid % ysize;
    const int rOff = tid / ysize;
    const int rStep = 256 / ysize;
    const int b0 = blockIdx.x * rowsPerBlock;
    float acc = 0.f;
    for (int b = b0 + rOff; b < b0 + rowsPerBlock; b += rStep)
        acc += T[(size_t)b * ysize + y] * w[b];
    atomicAdd(&score[y], acc);
}

// ---------------------------------------------------------------------------
// finish_mask: one block. full = (1-1/ysize)*rowsumH + scoreData;
// min-max normalize; hm = (norm < 0.5) ? 0 : 1.
// ---------------------------------------------------------------------------
__global__ __launch_bounds__(256) void finish_mask(
    const float* __restrict__ rowsumH, const float* __restrict__ scoreData,
    float* __restrict__ hm, int ysize)
{
    const int tid = threadIdx.x;
    __shared__ float sMin[256], sMax[256], sFull[256];
    float full = 0.f;
    if (tid < ysize) {
        float theta = 1.0f / (float)ysize;
        full = (1.0f - theta) * rowsumH[tid] + scoreData[tid];
        sFull[tid] = full;
    }
    sMin[tid] = (tid < ysize) ? full : 3.4e38f;
    sMax[tid] = (tid < ysize) ? full : -3.4e38f;
    __syncthreads();
    for (int st = 128; st > 0; st >>= 1) {
        if (tid < st) {
            sMin[tid] = fminf(sMin[tid], sMin[tid + st]);
            sMax[tid] = fmaxf(sMax[tid], sMax[tid + st]);
        }
        __syncthreads();
    }
    if (tid < ysize) {
        float mn = sMin[0], mx = sMax[0];
        float nrm = (sFull[tid] - mn) / (mx - mn + 1e-8f);
        hm[tid] = (nrm < 0.5f) ? 0.0f : 1.0f;
    }
}

// ---------------------------------------------------------------------------
// gemm_nt: C[M,N] = epilogue(A[M,K] @ B[N,K]^T)
// 64x64 tile, BK=16, 256 threads, 4x4 micro-tile per thread. fp32 VALU.
// epilogue: +bias[col] (if bias), relu (if doRelu), *mask[col] (if mask).
// M multiple of 64; N guarded (N=1000 case); K multiple of 16.
// ---------------------------------------------------------------------------
#define BM 64
#define BN 64
#define BK 16

__global__ __launch_bounds__(256) void gemm_nt(
    const float* __restrict__ A, const float* __restrict__ Bw,
    const float* __restrict__ bias, const float* __restrict__ mask,
    float* __restrict__ C, int M, int N, int K, int doRelu)
{
    __shared__ float As[BK][BM + 4];   // +4: keep float4 rows 16B-aligned
    __shared__ float Bs[BK][BN + 4];
    const int tid = threadIdx.x;
    const int bm = blockIdx.y * BM;
    const int bn = blockIdx.x * BN;
    const int ar = tid >> 2;           // 0..63 row within tile
    const int ac = (tid & 3) << 2;     // 0,4,8,12 : k offset of float4
    const int tx = tid & 15;
    const int ty = tid >> 4;

    float acc[4][4] = {{0.f}};

    const float* Ap = A + (size_t)(bm + ar) * K + ac;
    const bool bValid = (bn + ar) < N;
    const float* Bp = Bw + (size_t)(bValid ? (bn + ar) : 0) * K + ac;

    for (int k0 = 0; k0 < K; k0 += BK) {
        float4 av = *(const float4*)(Ap + k0);
        float4 bv = make_float4(0.f, 0.f, 0.f, 0.f);
        if (bValid) bv = *(const float4*)(Bp + k0);
        As[ac + 0][ar] = av.x; As[ac + 1][ar] = av.y;
        As[ac + 2][ar] = av.z; As[ac + 3][ar] = av.w;
        Bs[ac + 0][ar] = bv.x; Bs[ac + 1][ar] = bv.y;
        Bs[ac + 2][ar] = bv.z; Bs[ac + 3][ar] = bv.w;
        __syncthreads();
#pragma unroll
        for (int k = 0; k < BK; ++k) {
            const float4 a = *(const float4*)&As[k][ty << 2];
            const float4 b = *(const float4*)&Bs[k][tx << 2];
            acc[0][0] += a.x * b.x; acc[0][1] += a.x * b.y;
            acc[0][2] += a.x * b.z; acc[0][3] += a.x * b.w;
            acc[1][0] += a.y * b.x; acc[1][1] += a.y * b.y;
            acc[1][2] += a.y * b.z; acc[1][3] += a.y * b.w;
            acc[2][0] += a.z * b.x; acc[2][1] += a.z * b.y;
            acc[2][2] += a.z * b.z; acc[2][3] += a.z * b.w;
            acc[3][0] += a.w * b.x; acc[3][1] += a.w * b.y;
            acc[3][2] += a.w * b.z; acc[3][3] += a.w * b.w;
        }
        __syncthreads();
    }

#pragma unroll
    for (int i = 0; i < 4; ++i) {
        const int row = bm + (ty << 2) + i;
        const int col0 = bn + (tx << 2);
        float4 v;
        float* vv = (float*)&v;
#pragma unroll
        for (int j = 0; j < 4; ++j) {
            const int col = col0 + j;
            float val = acc[i][j];
            if (col < N) {
                if (bias) val += bias[col];
                if (doRelu) val = fmaxf(val, 0.f);
                if (mask) val *= mask[col];
            }
            vv[j] = val;
        }
        if (col0 + 3 < N) {
            *(float4*)(C + (size_t)row * N + col0) = v;
        } else {
#pragma unroll
            for (int j = 0; j < 4; ++j) {
                const int col = col0 + j;
                if (col < N) C[(size_t)row * N + col] = vv[j];
            }
        }
    }
}

// ---------------------------------------------------------------------------
extern "C" void kernel_launch(void* const* d_in, const int* in_sizes, int n_in,
                              void* d_out, int out_size, void* d_ws, size_t ws_size,
                              hipStream_t stream)
{
    const float* x     = (const float*)d_in[0];   // [8192,1024]
    const float* mask0 = (const float*)d_in[1];   // [256]
    const float* mask1 = (const float*)d_in[2];   // [128]
    const float* mask2 = (const float*)d_in[3];   // [64]
    const float* W1 = (const float*)d_in[4];  const float* b1 = (const float*)d_in[5];
    const float* W2 = (const float*)d_in[6];  const float* b2 = (const float*)d_in[7];
    const float* W3 = (const float*)d_in[8];  const float* b3 = (const float*)d_in[9];
    const float* W4 = (const float*)d_in[10]; const float* b4 = (const float*)d_in[11];
    const float* H1 = (const float*)d_in[12]; // [256,1024]
    const float* H2 = (const float*)d_in[13]; // [128,256]
    const float* H3 = (const float*)d_in[14]; // [64,128]

    float* out = (float*)d_out;                 // [8192,1000] flat
    float* hm0 = out + (size_t)8192 * 1000;     // 256
    float* hm1 = hm0 + 256;                     // 128
    float* hm2 = hm1 + 128;                     // 64

    // workspace layout (fp32), total ~23.1 MB
    float* ws = (float*)d_ws;
    float* X1 = ws;                         // 8192*256
    float* X2 = X1 + (size_t)8192 * 256;    // 8192*128
    float* X3 = X2 + (size_t)8192 * 128;    // 8192*64
    float* T  = X3 + (size_t)8192 * 64;     // 8192*256 (reused per layer)
    float* sv = T + (size_t)8192 * 256;     // 8192
    float* wv = sv + 8192;                  // 8192
    float* score   = wv + 8192;             // 256
    float* rowsumH = score + 256;           // 256

    auto hebbian = [&](const float* Xin, const float* H, float* hm, int K, int ysize) {
        // s[b] = rowsum(Xin_b)/||Xin_b||
        row_reduce<<<B_ROWS, 256, 0, stream>>>(Xin, nullptr, sv, K, 0);
        // T = Xin @ H^T  (row scale of xn cancels in yn)
        dim3 g(ysize / 64, B_ROWS / 64);
        gemm_nt<<<g, 256, 0, stream>>>(Xin, H, nullptr, nullptr, T, B_ROWS, ysize, K, 0);
        // w[b] = s[b]/||T_b||
        row_reduce<<<B_ROWS, 256, 0, stream>>>(T, sv, wv, ysize, 1);
        // score[y] = sum_b T[b,y]*w[b]
        zerov<<<1, 256, 0, stream>>>(score, ysize);
        colscore<<<B_ROWS / 64, 256, 0, stream>>>(T, wv, score, ysize, 64);
        // rowsum(H)
        row_reduce<<<ysize, 256, 0, stream>>>(H, nullptr, rowsumH, K, 2);
        finish_mask<<<1, 256, 0, stream>>>(rowsumH, score, hm, ysize);
    };

    // layer 1 (hebbian on x)
    hebbian(x, H1, hm0, 1024, 256);
    gemm_nt<<<dim3(4, 128), 256, 0, stream>>>(x, W1, b1, mask0, X1, 8192, 256, 1024, 1);
    // layer 2 (hebbian on X1)
    hebbian(X1, H2, hm1, 256, 128);
    gemm_nt<<<dim3(2, 128), 256, 0, stream>>>(X1, W2, b2, mask1, X2, 8192, 128, 256, 1);
    // layer 3 (hebbian on X2)
    hebbian(X2, H3, hm2, 64 * 2, 64);
    gemm_nt<<<dim3(1, 128), 256, 0, stream>>>(X2, W3, b3, mask2, X3, 8192, 64, 128, 1);
    // layer 4: out = relu(X3 @ W4^T + b4), N=1000 guarded
    gemm_nt<<<dim3(16, 128), 256, 0, stream>>>(X3, W4, b4, nullptr, out, 8192, 1000, 64, 1);
}

// Round 2
// 327.379 us; speedup vs baseline: 1.3654x; 1.3654x over previous
//
#include <hip/hip_runtime.h>
#include <math.h>

#define B_ROWS 8192
#define BM 64
#define BN 64
#define BK 16

// ---------------------------------------------------------------------------
// fused_gemm: one launch computes, for a layer with input A[M,K]:
//   T = A @ Wh^T                      (Hebbian pre-activation, no epilogue)
//   X = relu(A @ Ww^T + bias) * mask  (layer output)
//   sv[b]      = rowsum(A_b)/||A_b||  (computed by bx==0 blocks, free: they
//                                      already stream all K of their rows)
//   rowsumH[y] = rowsum(Wh_y)         (computed by by==0 H-tile blocks)
//   score[]    = zeroed by block (0,0) (consumed by hebb_score next)
// Grid: x = (Nh+Nw)/64 tiles (first Nh/64 are H-tiles), y = M/64.
// Nh, Nw multiples of 64 -> no column guards. 64x64 tile, 4x4 microtile.
// ---------------------------------------------------------------------------
__global__ __launch_bounds__(256) void fused_gemm(
    const float* __restrict__ A,
    const float* __restrict__ Wh, const float* __restrict__ Ww,
    const float* __restrict__ bias, const float* __restrict__ mask,
    float* __restrict__ T, float* __restrict__ X,
    float* __restrict__ sv, float* __restrict__ rowsumH,
    float* __restrict__ score,
    int M, int Nh, int Nw, int K)
{
    __shared__ float As[BK][BM + 4];
    __shared__ float Bs[BK][BN + 4];
    __shared__ float redS[BM][4], redQ[BM][4], redH[BM][4];

    const int tid = threadIdx.x;
    const int bx = blockIdx.x, by = blockIdx.y;
    const int nhT = Nh >> 6;
    const bool isH = bx < nhT;
    const int bm = by * BM;
    const int bn = (isH ? bx : bx - nhT) * BN;
    const bool doS = (bx == 0);
    const bool doH = isH && (by == 0);

    if (bx == 0 && by == 0 && tid < Nh) score[tid] = 0.f;

    const int ar = tid >> 2;            // 0..63: row within tile (for loads)
    const int ac = (tid & 3) << 2;      // 0,4,8,12: k-offset of float4
    const int tx = tid & 15;
    const int ty = tid >> 4;

    float acc[4][4] = {{0.f}};
    float aS = 0.f, aQ = 0.f, hS = 0.f;

    const float* Ap = A + (size_t)(bm + ar) * K + ac;
    const float* Bsrc = isH ? Wh : Ww;
    const float* Bp = Bsrc + (size_t)(bn + ar) * K + ac;

    for (int k0 = 0; k0 < K; k0 += BK) {
        float4 av = *(const float4*)(Ap + k0);
        float4 bv = *(const float4*)(Bp + k0);
        if (doS) {
            aS += av.x + av.y + av.z + av.w;
            aQ += av.x*av.x + av.y*av.y + av.z*av.z + av.w*av.w;
        }
        if (doH) hS += bv.x + bv.y + bv.z + bv.w;
        As[ac + 0][ar] = av.x; As[ac + 1][ar] = av.y;
        As[ac + 2][ar] = av.z; As[ac + 3][ar] = av.w;
        Bs[ac + 0][ar] = bv.x; Bs[ac + 1][ar] = bv.y;
        Bs[ac + 2][ar] = bv.z; Bs[ac + 3][ar] = bv.w;
        __syncthreads();
#pragma unroll
        for (int k = 0; k < BK; ++k) {
            const float4 a = *(const float4*)&As[k][ty << 2];
            const float4 b = *(const float4*)&Bs[k][tx << 2];
            acc[0][0] += a.x * b.x; acc[0][1] += a.x * b.y;
            acc[0][2] += a.x * b.z; acc[0][3] += a.x * b.w;
            acc[1][0] += a.y * b.x; acc[1][1] += a.y * b.y;
            acc[1][2] += a.y * b.z; acc[1][3] += a.y * b.w;
            acc[2][0] += a.z * b.x; acc[2][1] += a.z * b.y;
            acc[2][2] += a.z * b.z; acc[2][3] += a.z * b.w;
            acc[3][0] += a.w * b.x; acc[3][1] += a.w * b.y;
            acc[3][2] += a.w * b.z; acc[3][3] += a.w * b.w;
        }
        __syncthreads();
    }

    // side reductions (4 loader-threads per row -> LDS combine)
    if (doS) { redS[ar][tid & 3] = aS; redQ[ar][tid & 3] = aQ; }
    if (doH) { redH[ar][tid & 3] = hS; }
    __syncthreads();
    if (doS && (tid & 3) == 0) {
        float s = redS[ar][0] + redS[ar][1] + redS[ar][2] + redS[ar][3];
        float q = redQ[ar][0] + redQ[ar][1] + redQ[ar][2] + redQ[ar][3];
        sv[bm + ar] = s / sqrtf(q);
    }
    if (doH && (tid & 3) == 0) {
        rowsumH[bn + ar] = redH[ar][0] + redH[ar][1] + redH[ar][2] + redH[ar][3];
    }

    // epilogue
    float* C = isH ? T : X;
    const int ldc = isH ? Nh : Nw;
#pragma unroll
    for (int i = 0; i < 4; ++i) {
        const int row = bm + (ty << 2) + i;
        const int col0 = bn + (tx << 2);
        float4 v;
        float* vv = (float*)&v;
#pragma unroll
        for (int j = 0; j < 4; ++j) {
            float val = acc[i][j];
            if (!isH) {
                const int col = col0 + j;
                val = fmaxf(val + bias[col], 0.f) * mask[col];
            }
            vv[j] = val;
        }
        *(float4*)(C + (size_t)row * ldc + col0) = v;
    }
}

// ---------------------------------------------------------------------------
// hebb_score: per block, 64 rows of T. For each row:
//   w[b] = sv[b]/||T_b||  (wave shuffle-reduce of sumsq)
//   score[y] += T[b,y]*w[b]  (lane-local partials, LDS combine, 1 atomic/col)
// Reads T exactly once (replaces row_reduce + colscore).
// ---------------------------------------------------------------------------
__global__ __launch_bounds__(256) void hebb_score(
    const float* __restrict__ T, const float* __restrict__ sv,
    float* __restrict__ score, int ysize)
{
    const int tid = threadIdx.x;
    const int lane = tid & 63;
    const int wave = tid >> 6;
    const int vecsz = ysize >> 6;               // 4, 2, or 1
    const int b0 = blockIdx.x * 64;

    float accv[4] = {0.f, 0.f, 0.f, 0.f};
    for (int r = wave; r < 64; r += 4) {
        const float* Trow = T + (size_t)(b0 + r) * ysize;
        float vals[4] = {0.f, 0.f, 0.f, 0.f};
        if (vecsz == 4) {
            float4 t = *(const float4*)(Trow + (lane << 2));
            vals[0] = t.x; vals[1] = t.y; vals[2] = t.z; vals[3] = t.w;
        } else if (vecsz == 2) {
            float2 t = *(const float2*)(Trow + (lane << 1));
            vals[0] = t.x; vals[1] = t.y;
        } else {
            vals[0] = Trow[lane];
        }
        float sq = vals[0]*vals[0] + vals[1]*vals[1] + vals[2]*vals[2] + vals[3]*vals[3];
#pragma unroll
        for (int i = 1; i < 64; i <<= 1) sq += __shfl_xor(sq, i, 64);
        const float w = sv[b0 + r] / sqrtf(sq);
#pragma unroll
        for (int j = 0; j < 4; ++j) accv[j] += vals[j] * w;
    }

    __shared__ float sPart[4][256];
    for (int j = 0; j < vecsz; ++j) sPart[wave][lane * vecsz + j] = accv[j];
    __syncthreads();
    if (tid < ysize) {
        float p = sPart[0][tid] + sPart[1][tid] + sPart[2][tid] + sPart[3][tid];
        atomicAdd(&score[tid], p);
    }
}

// ---------------------------------------------------------------------------
// finish_mask: full = (1-1/ysize)*rowsumH + score; min-max norm; threshold.
// ---------------------------------------------------------------------------
__global__ __launch_bounds__(256) void finish_mask(
    const float* __restrict__ rowsumH, const float* __restrict__ scoreData,
    float* __restrict__ hm, int ysize)
{
    const int tid = threadIdx.x;
    __shared__ float sMin[256], sMax[256], sFull[256];
    float full = 0.f;
    if (tid < ysize) {
        float theta = 1.0f / (float)ysize;
        full = (1.0f - theta) * rowsumH[tid] + scoreData[tid];
        sFull[tid] = full;
    }
    sMin[tid] = (tid < ysize) ? full : 3.4e38f;
    sMax[tid] = (tid < ysize) ? full : -3.4e38f;
    __syncthreads();
    for (int st = 128; st > 0; st >>= 1) {
        if (tid < st) {
            sMin[tid] = fminf(sMin[tid], sMin[tid + st]);
            sMax[tid] = fmaxf(sMax[tid], sMax[tid + st]);
        }
        __syncthreads();
    }
    if (tid < ysize) {
        float mn = sMin[0], mx = sMax[0];
        float nrm = (sFull[tid] - mn) / (mx - mn + 1e-8f);
        hm[tid] = (nrm < 0.5f) ? 0.0f : 1.0f;
    }
}

// ---------------------------------------------------------------------------
// gemm_nt: plain GEMM for layer 4 (N=1000 guarded), bias+relu epilogue.
// ---------------------------------------------------------------------------
__global__ __launch_bounds__(256) void gemm_nt(
    const float* __restrict__ A, const float* __restrict__ Bw,
    const float* __restrict__ bias,
    float* __restrict__ C, int M, int N, int K)
{
    __shared__ float As[BK][BM + 4];
    __shared__ float Bs[BK][BN + 4];
    const int tid = threadIdx.x;
    const int bm = blockIdx.y * BM;
    const int bn = blockIdx.x * BN;
    const int ar = tid >> 2;
    const int ac = (tid & 3) << 2;
    const int tx = tid & 15;
    const int ty = tid >> 4;

    float acc[4][4] = {{0.f}};

    const float* Ap = A + (size_t)(bm + ar) * K + ac;
    const bool bValid = (bn + ar) < N;
    const float* Bp = Bw + (size_t)(bValid ? (bn + ar) : 0) * K + ac;

    for (int k0 = 0; k0 < K; k0 += BK) {
        float4 av = *(const float4*)(Ap + k0);
        float4 bv = make_float4(0.f, 0.f, 0.f, 0.f);
        if (bValid) bv = *(const float4*)(Bp + k0);
        As[ac + 0][ar] = av.x; As[ac + 1][ar] = av.y;
        As[ac + 2][ar] = av.z; As[ac + 3][ar] = av.w;
        Bs[ac + 0][ar] = bv.x; Bs[ac + 1][ar] = bv.y;
        Bs[ac + 2][ar] = bv.z; Bs[ac + 3][ar] = bv.w;
        __syncthreads();
#pragma unroll
        for (int k = 0; k < BK; ++k) {
            const float4 a = *(const float4*)&As[k][ty << 2];
            const float4 b = *(const float4*)&Bs[k][tx << 2];
            acc[0][0] += a.x * b.x; acc[0][1] += a.x * b.y;
            acc[0][2] += a.x * b.z; acc[0][3] += a.x * b.w;
            acc[1][0] += a.y * b.x; acc[1][1] += a.y * b.y;
            acc[1][2] += a.y * b.z; acc[1][3] += a.y * b.w;
            acc[2][0] += a.z * b.x; acc[2][1] += a.z * b.y;
            acc[2][2] += a.z * b.z; acc[2][3] += a.z * b.w;
            acc[3][0] += a.w * b.x; acc[3][1] += a.w * b.y;
            acc[3][2] += a.w * b.z; acc[3][3] += a.w * b.w;
        }
        __syncthreads();
    }

#pragma unroll
    for (int i = 0; i < 4; ++i) {
        const int row = bm + (ty << 2) + i;
        const int col0 = bn + (tx << 2);
        float4 v;
        float* vv = (float*)&v;
#pragma unroll
        for (int j = 0; j < 4; ++j) {
            const int col = col0 + j;
            float val = acc[i][j];
            if (col < N) val = fmaxf(val + bias[col], 0.f);
            vv[j] = val;
        }
        if (col0 + 3 < N) {
            *(float4*)(C + (size_t)row * N + col0) = v;
        } else {
#pragma unroll
            for (int j = 0; j < 4; ++j) {
                const int col = col0 + j;
                if (col < N) C[(size_t)row * N + col] = vv[j];
            }
        }
    }
}

// ---------------------------------------------------------------------------
extern "C" void kernel_launch(void* const* d_in, const int* in_sizes, int n_in,
                              void* d_out, int out_size, void* d_ws, size_t ws_size,
                              hipStream_t stream)
{
    const float* x     = (const float*)d_in[0];   // [8192,1024]
    const float* mask0 = (const float*)d_in[1];   // [256]
    const float* mask1 = (const float*)d_in[2];   // [128]
    const float* mask2 = (const float*)d_in[3];   // [64]
    const float* W1 = (const float*)d_in[4];  const float* b1 = (const float*)d_in[5];
    const float* W2 = (const float*)d_in[6];  const float* b2 = (const float*)d_in[7];
    const float* W3 = (const float*)d_in[8];  const float* b3 = (const float*)d_in[9];
    const float* W4 = (const float*)d_in[10]; const float* b4 = (const float*)d_in[11];
    const float* H1 = (const float*)d_in[12]; // [256,1024]
    const float* H2 = (const float*)d_in[13]; // [128,256]
    const float* H3 = (const float*)d_in[14]; // [64,128]

    float* out = (float*)d_out;                 // [8192,1000] flat
    float* hm0 = out + (size_t)8192 * 1000;     // 256
    float* hm1 = hm0 + 256;                     // 128
    float* hm2 = hm1 + 128;                     // 64

    float* ws = (float*)d_ws;
    float* X1 = ws;                         // 8192*256
    float* X2 = X1 + (size_t)8192 * 256;    // 8192*128
    float* X3 = X2 + (size_t)8192 * 128;    // 8192*64
    float* T  = X3 + (size_t)8192 * 64;     // 8192*256 (reused per layer)
    float* sv = T + (size_t)8192 * 256;     // 8192
    float* score   = sv + 8192;             // 256
    float* rowsumH = score + 256;           // 256

    // layer 1: T=x@H1^T, X1=relu(x@W1^T+b1)*mask0, s(x), rowsum(H1)
    fused_gemm<<<dim3(8, 128), 256, 0, stream>>>(
        x, H1, W1, b1, mask0, T, X1, sv, rowsumH, score, B_ROWS, 256, 256, 1024);
    hebb_score<<<128, 256, 0, stream>>>(T, sv, score, 256);
    finish_mask<<<1, 256, 0, stream>>>(rowsumH, score, hm0, 256);

    // layer 2
    fused_gemm<<<dim3(4, 128), 256, 0, stream>>>(
        X1, H2, W2, b2, mask1, T, X2, sv, rowsumH, score, B_ROWS, 128, 128, 256);
    hebb_score<<<128, 256, 0, stream>>>(T, sv, score, 128);
    finish_mask<<<1, 256, 0, stream>>>(rowsumH, score, hm1, 128);

    // layer 3
    fused_gemm<<<dim3(2, 128), 256, 0, stream>>>(
        X2, H3, W3, b3, mask2, T, X3, sv, rowsumH, score, B_ROWS, 64, 64, 128);
    hebb_score<<<128, 256, 0, stream>>>(T, sv, score, 64);
    finish_mask<<<1, 256, 0, stream>>>(rowsumH, score, hm2, 64);

    // layer 4: out = relu(X3 @ W4^T + b4), N=1000
    gemm_nt<<<dim3(16, 128), 256, 0, stream>>>(X3, W4, b4, out, B_ROWS, 1000, 64);
}

// Round 3
// 269.040 us; speedup vs baseline: 1.6615x; 1.2168x over previous
//
#include <hip/hip_runtime.h>
#include <math.h>

#define B_ROWS 8192

typedef __attribute__((ext_vector_type(8))) short short8;
typedef __attribute__((ext_vector_type(4))) float floatx4;

typedef __attribute__((address_space(1))) const unsigned int as1_uint;
typedef __attribute__((address_space(3))) unsigned int as3_uint;
#define GLD16(g, l) __builtin_amdgcn_global_load_lds((as1_uint*)(g), (as3_uint*)(l), 16, 0, 0)

__device__ __forceinline__ unsigned short f2bf(float f) {
    unsigned int u = __float_as_uint(f);
    return (unsigned short)((u + 0x7fffu + ((u >> 16) & 1u)) >> 16);
}
__device__ __forceinline__ float bf2f(unsigned short h) {
    return __uint_as_float(((unsigned int)h) << 16);
}

// ---------------------------------------------------------------------------
// convert_x: x[8192,1024] fp32 -> Ahl[8192,2048] bf16 ([hi | lo] per row).
// Also: sv[row] = rowsum/||row||; block 0 zeroes score + counters.
// ---------------------------------------------------------------------------
__global__ __launch_bounds__(256) void convert_x(
    const float* __restrict__ x, unsigned short* __restrict__ Ahl,
    float* __restrict__ sv, float* __restrict__ score, int* __restrict__ ctr)
{
    const int row = blockIdx.x, tid = threadIdx.x;
    if (row == 0) { if (tid < 8) ctr[tid] = 0; score[tid] = 0.f; }
    float4 v = *(const float4*)(x + (size_t)row * 1024 + (tid << 2));
    ushort4 h, l;
    h.x = f2bf(v.x); l.x = f2bf(v.x - bf2f(h.x));
    h.y = f2bf(v.y); l.y = f2bf(v.y - bf2f(h.y));
    h.z = f2bf(v.z); l.z = f2bf(v.z - bf2f(h.z));
    h.w = f2bf(v.w); l.w = f2bf(v.w - bf2f(h.w));
    *(ushort4*)(Ahl + (size_t)row * 2048 + (tid << 2)) = h;
    *(ushort4*)(Ahl + (size_t)row * 2048 + 1024 + (tid << 2)) = l;
    float sum = v.x + v.y + v.z + v.w;
    float sq  = v.x*v.x + v.y*v.y + v.z*v.z + v.w*v.w;
    __shared__ float sS[256], sQ[256];
    sS[tid] = sum; sQ[tid] = sq; __syncthreads();
    for (int st = 128; st > 0; st >>= 1) {
        if (tid < st) { sS[tid] += sS[tid + st]; sQ[tid] += sQ[tid + st]; }
        __syncthreads();
    }
    if (tid == 0) sv[row] = sS[0] / sqrtf(sQ[0]);
}

// ---------------------------------------------------------------------------
// convert_w: rows 0..255 = H1, 256..511 = W1 -> Bhl[512,2048] bf16 [hi|lo].
// rowsumH[row] for H rows.
// ---------------------------------------------------------------------------
__global__ __launch_bounds__(256) void convert_w(
    const float* __restrict__ H1, const float* __restrict__ W1,
    unsigned short* __restrict__ Bhl, float* __restrict__ rowsumH)
{
    const int row = blockIdx.x, tid = threadIdx.x;
    const float* src = (row < 256) ? (H1 + (size_t)row * 1024)
                                   : (W1 + (size_t)(row - 256) * 1024);
    float4 v = *(const float4*)(src + (tid << 2));
    ushort4 h, l;
    h.x = f2bf(v.x); l.x = f2bf(v.x - bf2f(h.x));
    h.y = f2bf(v.y); l.y = f2bf(v.y - bf2f(h.y));
    h.z = f2bf(v.z); l.z = f2bf(v.z - bf2f(h.z));
    h.w = f2bf(v.w); l.w = f2bf(v.w - bf2f(h.w));
    *(ushort4*)(Bhl + (size_t)row * 2048 + (tid << 2)) = h;
    *(ushort4*)(Bhl + (size_t)row * 2048 + 1024 + (tid << 2)) = l;
    __shared__ float sS[256];
    sS[tid] = v.x + v.y + v.z + v.w; __syncthreads();
    for (int st = 128; st > 0; st >>= 1) {
        if (tid < st) sS[tid] += sS[tid + st];
        __syncthreads();
    }
    if (tid == 0 && row < 256) rowsumH[row] = sS[0];
}

// ---------------------------------------------------------------------------
// mfma_l1: C[8192,512] = A@B^T via 3-segment split-bf16 (ah.bh + al.bh + ah.bl).
// cols 0..255 -> T raw; cols 256..511 -> X1 = relu(.+b1)*mask0.
// 128x128 tile, 4 waves x (64x64 wave-tile of 4x4 mfma_16x16x32), BK=32,
// global_load_lds(16B) staging, double-buffered LDS (grid=256 -> 1 block/CU).
// ---------------------------------------------------------------------------
__global__ __launch_bounds__(256) void mfma_l1(
    const unsigned short* __restrict__ Ahl, const unsigned short* __restrict__ Bhl,
    const float* __restrict__ b1, const float* __restrict__ mask0,
    float* __restrict__ T, float* __restrict__ X1)
{
    __shared__ __align__(16) char lds[32768];   // 2 bufs x (A 8K + B 8K)
    const int tid = threadIdx.x;
    const int w = tid >> 6, lane = tid & 63;
    const int bx = blockIdx.x, by = blockIdx.y;
    const int wm = w & 1, wn = w >> 1;
    const int q = lane >> 4, m16 = lane & 15;

    // staging: A-tile 128x32 bf16 = 8192B = 8 instrs of 1024B; wave w does 2.
    const int c0 = w * 128 + lane;     // chunk id, 4 chunks (16B) per 64B row
    const int c1 = c0 + 64;
    const size_t aOff0 = (size_t)(by * 128 + (c0 >> 2)) * 2048 + (size_t)((c0 & 3) << 3);
    const size_t aOff1 = (size_t)(by * 128 + (c1 >> 2)) * 2048 + (size_t)((c1 & 3) << 3);
    const size_t bOff0 = (size_t)(bx * 128 + (c0 >> 2)) * 2048 + (size_t)((c0 & 3) << 3);
    const size_t bOff1 = (size_t)(bx * 128 + (c1 >> 2)) * 2048 + (size_t)((c1 & 3) << 3);
    const int ldsI0 = w * 2048;        // instr (w*2) * 1024 bytes
    const int ldsI1 = ldsI0 + 1024;

    floatx4 acc[4][4] = {};

    // iteration -> (segment, k0): segments (aOff,bOff) = (0,0),(1024,0),(0,1024)
    auto kA = [](int it) { return (((it >> 5) == 1) ? 1024 : 0) + ((it & 31) << 5); };
    auto kB = [](int it) { return (((it >> 5) == 2) ? 1024 : 0) + ((it & 31) << 5); };

    auto stage = [&](int buf, int it) {
        const int a = kA(it), b = kB(it);
        char* base = lds + buf * 16384;
        GLD16(Ahl + aOff0 + a, base + ldsI0);
        GLD16(Ahl + aOff1 + a, base + ldsI1);
        GLD16(Bhl + bOff0 + b, base + 8192 + ldsI0);
        GLD16(Bhl + bOff1 + b, base + 8192 + ldsI1);
    };

    stage(0, 0);
    int cur = 0;
    for (int it = 0; it < 96; ++it) {
        __syncthreads();                       // drains staging of buf[cur]
        if (it + 1 < 96) stage(cur ^ 1, it + 1);   // async prefetch, overlaps compute
        const char* pb = lds + cur * 16384;
        short8 af[4], bfr[4];
#pragma unroll
        for (int i = 0; i < 4; ++i) {
            af[i]  = *(const short8*)(pb + (wm * 64 + i * 16 + m16) * 64 + q * 16);
            bfr[i] = *(const short8*)(pb + 8192 + (wn * 64 + i * 16 + m16) * 64 + q * 16);
        }
#pragma unroll
        for (int i = 0; i < 4; ++i)
#pragma unroll
            for (int j = 0; j < 4; ++j)
                acc[i][j] = __builtin_amdgcn_mfma_f32_16x16x32_bf16(af[i], bfr[j], acc[i][j], 0, 0, 0);
        cur ^= 1;
    }

    // epilogue: C/D layout col=lane&15, row=(lane>>4)*4+reg  [m89-verified]
#pragma unroll
    for (int i = 0; i < 4; ++i) {
        const int row0 = by * 128 + wm * 64 + i * 16 + q * 4;
#pragma unroll
        for (int j = 0; j < 4; ++j) {
            const int col = bx * 128 + wn * 64 + j * 16 + m16;
            floatx4 v = acc[i][j];
            if (col < 256) {
#pragma unroll
                for (int r = 0; r < 4; ++r) T[(size_t)(row0 + r) * 256 + col] = v[r];
            } else {
                const int c = col - 256;
                const float bb = b1[c], mm = mask0[c];
#pragma unroll
                for (int r = 0; r < 4; ++r)
                    X1[(size_t)(row0 + r) * 256 + c] = fmaxf(v[r] + bb, 0.f) * mm;
            }
        }
    }
}

// ---------------------------------------------------------------------------
// hebb_finish: per block 64 rows of T: w=sv/||T_row||, atomicAdd col-partials
// into score; last block (device-scope counter) does minmax mask -> hm.
// ---------------------------------------------------------------------------
__global__ __launch_bounds__(256) void hebb_finish(
    const float* __restrict__ T, const float* __restrict__ sv,
    const float* __restrict__ rowsumH, float* __restrict__ score,
    int* __restrict__ counter, float* __restrict__ hm, int ysize)
{
    const int tid = threadIdx.x, lane = tid & 63, wave = tid >> 6;
    const int vecsz = ysize >> 6;
    const int b0 = blockIdx.x * 64;
    float accv[4] = {0.f, 0.f, 0.f, 0.f};
    for (int r = wave; r < 64; r += 4) {
        const float* Trow = T + (size_t)(b0 + r) * ysize;
        float vals[4] = {0.f, 0.f, 0.f, 0.f};
        if (vecsz == 4) { float4 t = *(const float4*)(Trow + (lane << 2)); vals[0]=t.x; vals[1]=t.y; vals[2]=t.z; vals[3]=t.w; }
        else if (vecsz == 2) { float2 t = *(const float2*)(Trow + (lane << 1)); vals[0]=t.x; vals[1]=t.y; }
        else vals[0] = Trow[lane];
        float sq = vals[0]*vals[0] + vals[1]*vals[1] + vals[2]*vals[2] + vals[3]*vals[3];
#pragma unroll
        for (int i = 1; i < 64; i <<= 1) sq += __shfl_xor(sq, i, 64);
        const float wgt = sv[b0 + r] / sqrtf(sq);
        for (int j = 0; j < 4; ++j) accv[j] += vals[j] * wgt;
    }
    __shared__ float sPart[4][256];
    for (int j = 0; j < vecsz; ++j) sPart[wave][lane * vecsz + j] = accv[j];
    __syncthreads();
    if (tid < ysize)
        atomicAdd(&score[tid], sPart[0][tid] + sPart[1][tid] + sPart[2][tid] + sPart[3][tid]);
    __syncthreads();   // barrier drains the atomics (vmcnt) before counter bump
    __shared__ int lastFlag;
    if (tid == 0) {
        __threadfence();
        lastFlag = (atomicAdd(counter, 1) == (int)gridDim.x - 1) ? 1 : 0;
    }
    __syncthreads();
    if (!lastFlag) return;
    float full = 0.f;
    if (tid < ysize) {
        float s = atomicAdd(&score[tid], 0.f);   // coherent read of final sum
        full = (1.f - 1.f / (float)ysize) * rowsumH[tid] + s;
    }
    __shared__ float sMin[256], sMax[256];
    sMin[tid] = (tid < ysize) ? full : 3.4e38f;
    sMax[tid] = (tid < ysize) ? full : -3.4e38f;
    __syncthreads();
    for (int st = 128; st > 0; st >>= 1) {
        if (tid < st) { sMin[tid] = fminf(sMin[tid], sMin[tid+st]); sMax[tid] = fmaxf(sMax[tid], sMax[tid+st]); }
        __syncthreads();
    }
    if (tid < ysize) {
        float nrm = (full - sMin[0]) / (sMax[0] - sMin[0] + 1e-8f);
        hm[tid] = (nrm < 0.5f) ? 0.f : 1.f;
    }
}

// ---------------------------------------------------------------------------
// fused_gemm (fp32 vector, layers 2/3): T = A@Wh^T ; X = relu(A@Ww^T+b)*mask;
// sv from bx==0 loaders; rowsumH from by==0 H-tiles; zeroes score.
// ---------------------------------------------------------------------------
#define BM 64
#define BN 64
#define BK 16

__global__ __launch_bounds__(256) void fused_gemm(
    const float* __restrict__ A,
    const float* __restrict__ Wh, const float* __restrict__ Ww,
    const float* __restrict__ bias, const float* __restrict__ mask,
    float* __restrict__ T, float* __restrict__ X,
    float* __restrict__ sv, float* __restrict__ rowsumH,
    float* __restrict__ score,
    int M, int Nh, int Nw, int K)
{
    __shared__ float As[BK][BM + 4];
    __shared__ float Bs[BK][BN + 4];
    __shared__ float redS[BM][4], redQ[BM][4], redH[BM][4];

    const int tid = threadIdx.x;
    const int bx = blockIdx.x, by = blockIdx.y;
    const int nhT = Nh >> 6;
    const bool isH = bx < nhT;
    const int bm = by * BM;
    const int bn = (isH ? bx : bx - nhT) * BN;
    const bool doS = (bx == 0);
    const bool doH = isH && (by == 0);

    if (bx == 0 && by == 0 && tid < Nh) score[tid] = 0.f;

    const int ar = tid >> 2;
    const int ac = (tid & 3) << 2;
    const int tx = tid & 15;
    const int ty = tid >> 4;

    float acc[4][4] = {{0.f}};
    float aS = 0.f, aQ = 0.f, hS = 0.f;

    const float* Ap = A + (size_t)(bm + ar) * K + ac;
    const float* Bsrc = isH ? Wh : Ww;
    const float* Bp = Bsrc + (size_t)(bn + ar) * K + ac;

    for (int k0 = 0; k0 < K; k0 += BK) {
        float4 av = *(const float4*)(Ap + k0);
        float4 bv = *(const float4*)(Bp + k0);
        if (doS) {
            aS += av.x + av.y + av.z + av.w;
            aQ += av.x*av.x + av.y*av.y + av.z*av.z + av.w*av.w;
        }
        if (doH) hS += bv.x + bv.y + bv.z + bv.w;
        As[ac + 0][ar] = av.x; As[ac + 1][ar] = av.y;
        As[ac + 2][ar] = av.z; As[ac + 3][ar] = av.w;
        Bs[ac + 0][ar] = bv.x; Bs[ac + 1][ar] = bv.y;
        Bs[ac + 2][ar] = bv.z; Bs[ac + 3][ar] = bv.w;
        __syncthreads();
#pragma unroll
        for (int k = 0; k < BK; ++k) {
            const float4 a = *(const float4*)&As[k][ty << 2];
            const float4 b = *(const float4*)&Bs[k][tx << 2];
            acc[0][0] += a.x * b.x; acc[0][1] += a.x * b.y;
            acc[0][2] += a.x * b.z; acc[0][3] += a.x * b.w;
            acc[1][0] += a.y * b.x; acc[1][1] += a.y * b.y;
            acc[1][2] += a.y * b.z; acc[1][3] += a.y * b.w;
            acc[2][0] += a.z * b.x; acc[2][1] += a.z * b.y;
            acc[2][2] += a.z * b.z; acc[2][3] += a.z * b.w;
            acc[3][0] += a.w * b.x; acc[3][1] += a.w * b.y;
            acc[3][2] += a.w * b.z; acc[3][3] += a.w * b.w;
        }
        __syncthreads();
    }

    if (doS) { redS[ar][tid & 3] = aS; redQ[ar][tid & 3] = aQ; }
    if (doH) { redH[ar][tid & 3] = hS; }
    __syncthreads();
    if (doS && (tid & 3) == 0) {
        float s = redS[ar][0] + redS[ar][1] + redS[ar][2] + redS[ar][3];
        float qq = redQ[ar][0] + redQ[ar][1] + redQ[ar][2] + redQ[ar][3];
        sv[bm + ar] = s / sqrtf(qq);
    }
    if (doH && (tid & 3) == 0) {
        rowsumH[bn + ar] = redH[ar][0] + redH[ar][1] + redH[ar][2] + redH[ar][3];
    }

    float* C = isH ? T : X;
    const int ldc = isH ? Nh : Nw;
#pragma unroll
    for (int i = 0; i < 4; ++i) {
        const int row = bm + (ty << 2) + i;
        const int col0 = bn + (tx << 2);
        float4 v;
        float* vv = (float*)&v;
#pragma unroll
        for (int j = 0; j < 4; ++j) {
            float val = acc[i][j];
            if (!isH) {
                const int col = col0 + j;
                val = fmaxf(val + bias[col], 0.f) * mask[col];
            }
            vv[j] = val;
        }
        *(float4*)(C + (size_t)row * ldc + col0) = v;
    }
}

// ---------------------------------------------------------------------------
// gemm_nt: layer 4 (N=1000 guarded), bias+relu.
// ---------------------------------------------------------------------------
__global__ __launch_bounds__(256) void gemm_nt(
    const float* __restrict__ A, const float* __restrict__ Bw,
    const float* __restrict__ bias,
    float* __restrict__ C, int M, int N, int K)
{
    __shared__ float As[BK][BM + 4];
    __shared__ float Bs[BK][BN + 4];
    const int tid = threadIdx.x;
    const int bm = blockIdx.y * BM;
    const int bn = blockIdx.x * BN;
    const int ar = tid >> 2;
    const int ac = (tid & 3) << 2;
    const int tx = tid & 15;
    const int ty = tid >> 4;

    float acc[4][4] = {{0.f}};

    const float* Ap = A + (size_t)(bm + ar) * K + ac;
    const bool bValid = (bn + ar) < N;
    const float* Bp = Bw + (size_t)(bValid ? (bn + ar) : 0) * K + ac;

    for (int k0 = 0; k0 < K; k0 += BK) {
        float4 av = *(const float4*)(Ap + k0);
        float4 bv = make_float4(0.f, 0.f, 0.f, 0.f);
        if (bValid) bv = *(const float4*)(Bp + k0);
        As[ac + 0][ar] = av.x; As[ac + 1][ar] = av.y;
        As[ac + 2][ar] = av.z; As[ac + 3][ar] = av.w;
        Bs[ac + 0][ar] = bv.x; Bs[ac + 1][ar] = bv.y;
        Bs[ac + 2][ar] = bv.z; Bs[ac + 3][ar] = bv.w;
        __syncthreads();
#pragma unroll
        for (int k = 0; k < BK; ++k) {
            const float4 a = *(const float4*)&As[k][ty << 2];
            const float4 b = *(const float4*)&Bs[k][tx << 2];
            acc[0][0] += a.x * b.x; acc[0][1] += a.x * b.y;
            acc[0][2] += a.x * b.z; acc[0][3] += a.x * b.w;
            acc[1][0] += a.y * b.x; acc[1][1] += a.y * b.y;
            acc[1][2] += a.y * b.z; acc[1][3] += a.y * b.w;
            acc[2][0] += a.z * b.x; acc[2][1] += a.z * b.y;
            acc[2][2] += a.z * b.z; acc[2][3] += a.z * b.w;
            acc[3][0] += a.w * b.x; acc[3][1] += a.w * b.y;
            acc[3][2] += a.w * b.z; acc[3][3] += a.w * b.w;
        }
        __syncthreads();
    }

#pragma unroll
    for (int i = 0; i < 4; ++i) {
        const int row = bm + (ty << 2) + i;
        const int col0 = bn + (tx << 2);
        float4 v;
        float* vv = (float*)&v;
#pragma unroll
        for (int j = 0; j < 4; ++j) {
            const int col = col0 + j;
            float val = acc[i][j];
            if (col < N) val = fmaxf(val + bias[col], 0.f);
            vv[j] = val;
        }
        if (col0 + 3 < N) {
            *(float4*)(C + (size_t)row * N + col0) = v;
        } else {
#pragma unroll
            for (int j = 0; j < 4; ++j) {
                const int col = col0 + j;
                if (col < N) C[(size_t)row * N + col] = vv[j];
            }
        }
    }
}

// ---------------------------------------------------------------------------
extern "C" void kernel_launch(void* const* d_in, const int* in_sizes, int n_in,
                              void* d_out, int out_size, void* d_ws, size_t ws_size,
                              hipStream_t stream)
{
    const float* x     = (const float*)d_in[0];
    const float* mask0 = (const float*)d_in[1];
    const float* mask1 = (const float*)d_in[2];
    const float* mask2 = (const float*)d_in[3];
    const float* W1 = (const float*)d_in[4];  const float* b1 = (const float*)d_in[5];
    const float* W2 = (const float*)d_in[6];  const float* b2 = (const float*)d_in[7];
    const float* W3 = (const float*)d_in[8];  const float* b3 = (const float*)d_in[9];
    const float* W4 = (const float*)d_in[10]; const float* b4 = (const float*)d_in[11];
    const float* H1 = (const float*)d_in[12];
    const float* H2 = (const float*)d_in[13];
    const float* H3 = (const float*)d_in[14];

    float* out = (float*)d_out;
    float* hm0 = out + (size_t)8192 * 1000;
    float* hm1 = hm0 + 256;
    float* hm2 = hm1 + 128;

    // ws layout (floats). Ahl region is dead after mfma_l1 -> X2/X3 alias it.
    float* ws = (float*)d_ws;
    unsigned short* Ahl = (unsigned short*)ws;            // 8192*2048 bf16 = 8388608 f
    float* fb = ws + 8388608;
    unsigned short* Bhl = (unsigned short*)fb;            // 512*2048 bf16 = 524288 f
    float* T  = fb + 524288;                              // 8192*256
    float* X1 = T + (size_t)8192 * 256;                   // 8192*256
    float* sv = X1 + (size_t)8192 * 256;                  // 8192
    float* score   = sv + 8192;                           // 256
    float* rowsumH = score + 256;                         // 256
    int*   ctr     = (int*)(rowsumH + 256);               // 8
    float* X2 = ws;                                       // alias (8192*128)
    float* X3 = ws + (size_t)8192 * 128;                  // alias (8192*64)

    // layer 1 (split-bf16 MFMA)
    convert_x<<<B_ROWS, 256, 0, stream>>>(x, Ahl, sv, score, ctr);
    convert_w<<<512, 256, 0, stream>>>(H1, W1, Bhl, rowsumH);
    mfma_l1<<<dim3(4, 64), 256, 0, stream>>>(Ahl, Bhl, b1, mask0, T, X1);
    hebb_finish<<<128, 256, 0, stream>>>(T, sv, rowsumH, score, &ctr[0], hm0, 256);

    // layer 2 (fp32 vector)
    fused_gemm<<<dim3(4, 128), 256, 0, stream>>>(
        X1, H2, W2, b2, mask1, T, X2, sv, rowsumH, score, B_ROWS, 128, 128, 256);
    hebb_finish<<<128, 256, 0, stream>>>(T, sv, rowsumH, score, &ctr[1], hm1, 128);

    // layer 3
    fused_gemm<<<dim3(2, 128), 256, 0, stream>>>(
        X2, H3, W3, b3, mask2, T, X3, sv, rowsumH, score, B_ROWS, 64, 64, 128);
    hebb_finish<<<128, 256, 0, stream>>>(T, sv, rowsumH, score, &ctr[2], hm2, 64);

    // layer 4
    gemm_nt<<<dim3(16, 128), 256, 0, stream>>>(X3, W4, b4, out, B_ROWS, 1000, 64);
}

// Round 4
// 260.319 us; speedup vs baseline: 1.7171x; 1.0335x over previous
//
#include <hip/hip_runtime.h>
#include <math.h>

typedef __attribute__((ext_vector_type(8))) short short8;
typedef __attribute__((ext_vector_type(4))) float floatx4;

typedef __attribute__((address_space(1))) const unsigned int as1_uint;
typedef __attribute__((address_space(3))) unsigned int as3_uint;
#define GLD16(g, l) __builtin_amdgcn_global_load_lds((as1_uint*)(g), (as3_uint*)(l), 16, 0, 0)

__device__ __forceinline__ unsigned short f2bf(float f) {
    unsigned int u = __float_as_uint(f);
    return (unsigned short)((u + 0x7fffu + ((u >> 16) & 1u)) >> 16);
}
__device__ __forceinline__ float bf2f(unsigned short h) {
    return __uint_as_float(((unsigned int)h) << 16);
}

// ---------------------------------------------------------------------------
// convert_x: x[8192,1024] fp32 -> Axhl[8192,2048] bf16 ([hi|lo] per row).
// rs1/rq1 = rowsum/rowsumsq (exact fp32). Zeroes rs2/rq2/rs3/rq3, score, ctr.
// ---------------------------------------------------------------------------
__global__ __launch_bounds__(256) void convert_x(
    const float* __restrict__ x, unsigned short* __restrict__ Axhl,
    float* __restrict__ rs1, float* __restrict__ rq1,
    float* __restrict__ rs2, float* __restrict__ rq2,
    float* __restrict__ rs3, float* __restrict__ rq3,
    float* __restrict__ score, int* __restrict__ ctr)
{
    const int row = blockIdx.x, tid = threadIdx.x;
    if (row == 0) { score[tid] = 0.f; if (tid < 8) ctr[tid] = 0; }
    if (tid == 0) { rs2[row] = 0.f; rq2[row] = 0.f; rs3[row] = 0.f; rq3[row] = 0.f; }
    float4 v = *(const float4*)(x + (size_t)row * 1024 + (tid << 2));
    ushort4 h, l;
    h.x = f2bf(v.x); l.x = f2bf(v.x - bf2f(h.x));
    h.y = f2bf(v.y); l.y = f2bf(v.y - bf2f(h.y));
    h.z = f2bf(v.z); l.z = f2bf(v.z - bf2f(h.z));
    h.w = f2bf(v.w); l.w = f2bf(v.w - bf2f(h.w));
    *(ushort4*)(Axhl + (size_t)row * 2048 + (tid << 2)) = h;
    *(ushort4*)(Axhl + (size_t)row * 2048 + 1024 + (tid << 2)) = l;
    float s = v.x + v.y + v.z + v.w;
    float qq = v.x*v.x + v.y*v.y + v.z*v.z + v.w*v.w;
#pragma unroll
    for (int d = 1; d < 64; d <<= 1) { s += __shfl_xor(s, d, 64); qq += __shfl_xor(qq, d, 64); }
    __shared__ float sS[4], sQ[4];
    if ((tid & 63) == 0) { sS[tid >> 6] = s; sQ[tid >> 6] = qq; }
    __syncthreads();
    if (tid == 0) {
        rs1[row] = sS[0] + sS[1] + sS[2] + sS[3];
        rq1[row] = sQ[0] + sQ[1] + sQ[2] + sQ[3];
    }
}

// ---------------------------------------------------------------------------
// convert_w: all weights -> bf16 [hi|lo] packs; rowsums of H1/H2/H3.
// blocks: 0-255 H1, 256-511 W1, 512-639 H2, 640-767 W2, 768-831 H3,
//         832-895 W3, 896-1919 W4 (rows>=1000 zero-padded).
// ---------------------------------------------------------------------------
__global__ __launch_bounds__(256) void convert_w(
    const float* __restrict__ H1, const float* __restrict__ W1,
    const float* __restrict__ H2, const float* __restrict__ W2,
    const float* __restrict__ H3, const float* __restrict__ W3,
    const float* __restrict__ W4,
    unsigned short* __restrict__ B1, unsigned short* __restrict__ B2,
    unsigned short* __restrict__ B3, unsigned short* __restrict__ B4,
    float* __restrict__ rsH1, float* __restrict__ rsH2, float* __restrict__ rsH3)
{
    const int b = blockIdx.x, tid = threadIdx.x;
    const float* src; unsigned short* dst; int K; float* rsum = nullptr;
    if (b < 256)      { K = 1024; src = H1 + (size_t)b * 1024;        dst = B1 + (size_t)b * 2048;        rsum = rsH1 + b; }
    else if (b < 512) { K = 1024; src = W1 + (size_t)(b - 256) * 1024; dst = B1 + (size_t)b * 2048; }
    else if (b < 640) { K = 256;  src = H2 + (size_t)(b - 512) * 256;  dst = B2 + (size_t)(b - 512) * 512; rsum = rsH2 + (b - 512); }
    else if (b < 768) { K = 256;  src = W2 + (size_t)(b - 640) * 256;  dst = B2 + (size_t)(b - 512) * 512; }
    else if (b < 832) { K = 128;  src = H3 + (size_t)(b - 768) * 128;  dst = B3 + (size_t)(b - 768) * 256; rsum = rsH3 + (b - 768); }
    else if (b < 896) { K = 128;  src = W3 + (size_t)(b - 832) * 128;  dst = B3 + (size_t)(b - 768) * 256; }
    else { K = 64; int r = b - 896; src = (r < 1000) ? (W4 + (size_t)r * 64) : nullptr; dst = B4 + (size_t)r * 128; }

    float lsum = 0.f;
    if (tid * 4 < K) {
        float4 v = src ? *(const float4*)(src + tid * 4) : make_float4(0.f, 0.f, 0.f, 0.f);
        ushort4 h, l;
        h.x = f2bf(v.x); l.x = f2bf(v.x - bf2f(h.x));
        h.y = f2bf(v.y); l.y = f2bf(v.y - bf2f(h.y));
        h.z = f2bf(v.z); l.z = f2bf(v.z - bf2f(h.z));
        h.w = f2bf(v.w); l.w = f2bf(v.w - bf2f(h.w));
        *(ushort4*)(dst + tid * 4) = h;
        *(ushort4*)(dst + K + tid * 4) = l;
        lsum = v.x + v.y + v.z + v.w;
    }
    if (rsum) {
#pragma unroll
        for (int d = 1; d < 64; d <<= 1) lsum += __shfl_xor(lsum, d, 64);
        __shared__ float sS[4];
        if ((tid & 63) == 0) sS[tid >> 6] = lsum;
        __syncthreads();
        if (tid == 0) *rsum = sS[0] + sS[1] + sS[2] + sS[3];
    }
}

// ---------------------------------------------------------------------------
// mfma_layer<KW>: C[8192, Nh+Nw] = A @ B^T via 3-segment split-bf16
// (ah.bh + al.bh + ah.bl). A rows [hi(K)|lo(K)], B rows likewise; stride 4K B.
// 128x128 tile, 4 waves (2x2), 4x4 of 16x16x32 mfma per wave, KW k-elems per
// iter, single 2*TILEB LDS buffer, global_load_lds(16B) staging with XOR
// chunk swizzle (bank-conflict-free ds_read_b128), XCD-aware block swizzle.
// Epilogue: cols<Nh -> T fp32; else X = relu(+bias)*mask -> Xhl bf16 hi/lo +
// rs/rq row-reduction atomics; outF mode (L4): relu(+bias) -> fp32, ld NwReal.
// ---------------------------------------------------------------------------
template<int KW>
__global__ __launch_bounds__(256) void mfma_layer(
    const unsigned short* __restrict__ Ag, const unsigned short* __restrict__ Bg,
    const float* __restrict__ bias, const float* __restrict__ maskv,
    float* __restrict__ T, unsigned short* __restrict__ Xhl,
    float* __restrict__ outF,
    float* __restrict__ rs, float* __restrict__ rq,
    int K, int Nh, int Nw, int NwReal)
{
    constexpr int CPR = (KW * 2) / 16;   // 16-B chunks per LDS row (16 | 8)
    constexpr int RPI = 64 / CPR;        // rows per 1024-B staging instr (4 | 8)
    constexpr int NIA = 128 / RPI;       // staging instrs per matrix tile (32 | 16)
    constexpr int PERW = NIA / 4;        // per wave (8 | 4)
    constexpr int TILEB = 128 * KW * 2;  // bytes per matrix tile (32K | 16K)
    constexpr int HS = KW / 32;          // mfma k-steps per iter (4 | 2)
    __shared__ __align__(16) char lds[2 * TILEB];

    const int tid = threadIdx.x;
    const int w = tid >> 6, lane = tid & 63;
    const int q = lane >> 4, m16 = lane & 15;
    const int wm = w & 1, wn = w >> 1;

    // XCD swizzle: same-by blocks land on the same XCD (lin%8 heuristic)
    const int lin = blockIdx.y * gridDim.x + blockIdx.x;
    const int g = lin & 7, s = lin >> 3;
    const int by = g + ((s & 7) << 3);   // gridDim.y must be 64
    const int bx = s >> 3;

    const int strideB = 4 * K;           // bytes per hl row
    const int u = lane % CPR, v = lane / CPR;
    int aOff[PERW], bOff[PERW];
#pragma unroll
    for (int t0 = 0; t0 < PERW; ++t0) {
        const int t = w * PERW + t0;
        const int r = t * RPI + v;
        const int c = u ^ (r & (CPR - 1));
        aOff[t0] = (by * 128 + r) * strideB + c * 16;
        bOff[t0] = (bx * 128 + r) * strideB + c * 16;
    }

    const char* Ab = (const char*)Ag;
    const char* Bb = (const char*)Bg;
    floatx4 acc[4][4] = {};

    for (int seg = 0; seg < 3; ++seg) {
        const int aS = (seg == 1) ? 2 * K : 0;
        const int bS = (seg == 2) ? 2 * K : 0;
        for (int k0 = 0; k0 < K; k0 += KW) {
            const int ka = aS + 2 * k0, kb = bS + 2 * k0;
#pragma unroll
            for (int t0 = 0; t0 < PERW; ++t0) {
                const int t = w * PERW + t0;
                GLD16(Ab + aOff[t0] + ka, lds + t * 1024);
                GLD16(Bb + bOff[t0] + kb, lds + TILEB + t * 1024);
            }
            __syncthreads();    // drain staging
#pragma unroll
            for (int h = 0; h < HS; ++h) {
                short8 af[4], bfr[4];
#pragma unroll
                for (int i = 0; i < 4; ++i) {
                    const int ra = wm * 64 + i * 16 + m16;
                    af[i] = *(const short8*)(lds + ra * (2 * KW)
                              + (((h * 4 + q) ^ (ra & (CPR - 1))) << 4));
                    const int rb = wn * 64 + i * 16 + m16;
                    bfr[i] = *(const short8*)(lds + TILEB + rb * (2 * KW)
                              + (((h * 4 + q) ^ (rb & (CPR - 1))) << 4));
                }
#pragma unroll
                for (int i = 0; i < 4; ++i)
#pragma unroll
                    for (int j = 0; j < 4; ++j)
                        acc[i][j] = __builtin_amdgcn_mfma_f32_16x16x32_bf16(af[i], bfr[j], acc[i][j], 0, 0, 0);
            }
            __syncthreads();    // all reads done before next overwrite
        }
    }

    // epilogue; C/D layout: col = lane&15, row = q*4 + reg
    const int colW = bx * 128 + wn * 64;
    const bool isHwave = (outF == nullptr) && (colW < Nh);
#pragma unroll
    for (int i = 0; i < 4; ++i) {
        const int row0 = by * 128 + wm * 64 + i * 16 + q * 4;
        float rsum[4] = {0.f, 0.f, 0.f, 0.f}, rqsum[4] = {0.f, 0.f, 0.f, 0.f};
#pragma unroll
        for (int j = 0; j < 4; ++j) {
            const int col = colW + j * 16 + m16;
            floatx4 vv = acc[i][j];
            if (outF) {
                if (col < NwReal) {
                    const float bb = bias[col];
#pragma unroll
                    for (int rg = 0; rg < 4; ++rg)
                        outF[(size_t)(row0 + rg) * NwReal + col] = fmaxf(vv[rg] + bb, 0.f);
                }
            } else if (isHwave) {
#pragma unroll
                for (int rg = 0; rg < 4; ++rg)
                    T[(size_t)(row0 + rg) * Nh + col] = vv[rg];
            } else {
                const int c = col - Nh;
                const float bb = bias[c], mm = maskv[c];
#pragma unroll
                for (int rg = 0; rg < 4; ++rg) {
                    const float xv = fmaxf(vv[rg] + bb, 0.f) * mm;
                    const unsigned short hi = f2bf(xv);
                    const unsigned short lo = f2bf(xv - bf2f(hi));
                    Xhl[(size_t)(row0 + rg) * (2 * Nw) + c] = hi;
                    Xhl[(size_t)(row0 + rg) * (2 * Nw) + Nw + c] = lo;
                    rsum[rg] += xv; rqsum[rg] += xv * xv;
                }
            }
        }
        if (rs && !isHwave && !outF) {
#pragma unroll
            for (int rg = 0; rg < 4; ++rg) {
                float a_ = rsum[rg], b_ = rqsum[rg];
#pragma unroll
                for (int d = 1; d < 16; d <<= 1) {
                    a_ += __shfl_xor(a_, d, 64);
                    b_ += __shfl_xor(b_, d, 64);
                }
                if (m16 == 0) {
                    atomicAdd(&rs[row0 + rg], a_);
                    atomicAdd(&rq[row0 + rg], b_);
                }
            }
        }
    }
}

// ---------------------------------------------------------------------------
// hebb_finish: per block 64 rows of T: wgt = (rs/sqrt(rq))/||T_row||;
// score[y] += T[b,y]*wgt[b]; last block computes minmax mask -> hm and
// re-zeroes score for the next layer.
// ---------------------------------------------------------------------------
__global__ __launch_bounds__(256) void hebb_finish(
    const float* __restrict__ T, const float* __restrict__ rs,
    const float* __restrict__ rq, const float* __restrict__ rowsumH,
    float* __restrict__ score, int* __restrict__ counter,
    float* __restrict__ hm, int ysize)
{
    const int tid = threadIdx.x, lane = tid & 63, wave = tid >> 6;
    const int vecsz = ysize >> 6;
    const int b0 = blockIdx.x * 64;
    float accv[4] = {0.f, 0.f, 0.f, 0.f};
    for (int r = wave; r < 64; r += 4) {
        const float* Trow = T + (size_t)(b0 + r) * ysize;
        float vals[4] = {0.f, 0.f, 0.f, 0.f};
        if (vecsz == 4) { float4 t = *(const float4*)(Trow + (lane << 2)); vals[0]=t.x; vals[1]=t.y; vals[2]=t.z; vals[3]=t.w; }
        else if (vecsz == 2) { float2 t = *(const float2*)(Trow + (lane << 1)); vals[0]=t.x; vals[1]=t.y; }
        else vals[0] = Trow[lane];
        float sq = vals[0]*vals[0] + vals[1]*vals[1] + vals[2]*vals[2] + vals[3]*vals[3];
#pragma unroll
        for (int i = 1; i < 64; i <<= 1) sq += __shfl_xor(sq, i, 64);
        const float wgt = rs[b0 + r] / (sqrtf(rq[b0 + r]) * sqrtf(sq));
        for (int j = 0; j < 4; ++j) accv[j] += vals[j] * wgt;
    }
    __shared__ float sPart[4][256];
    for (int j = 0; j < vecsz; ++j) sPart[wave][lane * vecsz + j] = accv[j];
    __syncthreads();
    if (tid < ysize)
        atomicAdd(&score[tid], sPart[0][tid] + sPart[1][tid] + sPart[2][tid] + sPart[3][tid]);
    __syncthreads();
    __shared__ int lastFlag;
    if (tid == 0) {
        __threadfence();
        lastFlag = (atomicAdd(counter, 1) == (int)gridDim.x - 1) ? 1 : 0;
    }
    __syncthreads();
    if (!lastFlag) return;
    float full = 0.f;
    if (tid < ysize) {
        float sc = atomicAdd(&score[tid], 0.f);
        full = (1.f - 1.f / (float)ysize) * rowsumH[tid] + sc;
    }
    __shared__ float sMin[256], sMax[256];
    sMin[tid] = (tid < ysize) ? full : 3.4e38f;
    sMax[tid] = (tid < ysize) ? full : -3.4e38f;
    __syncthreads();
    for (int st = 128; st > 0; st >>= 1) {
        if (tid < st) { sMin[tid] = fminf(sMin[tid], sMin[tid+st]); sMax[tid] = fmaxf(sMax[tid], sMax[tid+st]); }
        __syncthreads();
    }
    if (tid < ysize) {
        float nrm = (full - sMin[0]) / (sMax[0] - sMin[0] + 1e-8f);
        hm[tid] = (nrm < 0.5f) ? 0.f : 1.f;
    }
    score[tid] = 0.f;   // ready for next layer
}

// ---------------------------------------------------------------------------
extern "C" void kernel_launch(void* const* d_in, const int* in_sizes, int n_in,
                              void* d_out, int out_size, void* d_ws, size_t ws_size,
                              hipStream_t stream)
{
    const float* x     = (const float*)d_in[0];
    const float* mask0 = (const float*)d_in[1];
    const float* mask1 = (const float*)d_in[2];
    const float* mask2 = (const float*)d_in[3];
    const float* W1 = (const float*)d_in[4];  const float* b1 = (const float*)d_in[5];
    const float* W2 = (const float*)d_in[6];  const float* b2 = (const float*)d_in[7];
    const float* W3 = (const float*)d_in[8];  const float* b3 = (const float*)d_in[9];
    const float* W4 = (const float*)d_in[10]; const float* b4 = (const float*)d_in[11];
    const float* H1 = (const float*)d_in[12];
    const float* H2 = (const float*)d_in[13];
    const float* H3 = (const float*)d_in[14];

    float* out = (float*)d_out;
    float* hm0 = out + (size_t)8192 * 1000;
    float* hm1 = hm0 + 256;
    float* hm2 = hm1 + 128;

    // ws layout (float units). Axhl (32 MB) dead after mfma L1 -> X2hl/X3hl alias it.
    float* ws = (float*)d_ws;
    unsigned short* Axhl = (unsigned short*)ws;                 // 8192*2048 bf16 (8388608 f)
    unsigned short* X2hl = (unsigned short*)ws;                 // alias: 8192*256 bf16
    unsigned short* X3hl = (unsigned short*)(ws + 1048576);     // alias: 8192*128 bf16
    float* p = ws + 8388608;
    unsigned short* B1 = (unsigned short*)p;  p += 524288;      // 512*2048
    unsigned short* B2 = (unsigned short*)p;  p += 65536;       // 256*512
    unsigned short* B3 = (unsigned short*)p;  p += 16384;       // 128*256
    unsigned short* B4 = (unsigned short*)p;  p += 65536;       // 1024*128
    float* T    = p;  p += 2097152;                             // 8192*256 fp32
    unsigned short* X1hl = (unsigned short*)p; p += 2097152;    // 8192*512 bf16
    float* rs1 = p; p += 8192;  float* rq1 = p; p += 8192;
    float* rs2 = p; p += 8192;  float* rq2 = p; p += 8192;
    float* rs3 = p; p += 8192;  float* rq3 = p; p += 8192;
    float* rsH1 = p; p += 256;  float* rsH2 = p; p += 128;  float* rsH3 = p; p += 64;
    float* score = p; p += 256;
    int* ctr = (int*)p;

    convert_x<<<8192, 256, 0, stream>>>(x, Axhl, rs1, rq1, rs2, rq2, rs3, rq3, score, ctr);
    convert_w<<<1920, 256, 0, stream>>>(H1, W1, H2, W2, H3, W3, W4, B1, B2, B3, B4, rsH1, rsH2, rsH3);

    // layer 1: T = x@H1^T, X1 = relu(x@W1^T+b1)*mask0 (+rs2/rq2)
    mfma_layer<128><<<dim3(4, 64), 256, 0, stream>>>(
        Axhl, B1, b1, mask0, T, X1hl, nullptr, rs2, rq2, 1024, 256, 256, 256);
    hebb_finish<<<128, 256, 0, stream>>>(T, rs1, rq1, rsH1, score, ctr + 0, hm0, 256);

    // layer 2
    mfma_layer<128><<<dim3(2, 64), 256, 0, stream>>>(
        X1hl, B2, b2, mask1, T, X2hl, nullptr, rs3, rq3, 256, 128, 128, 128);
    hebb_finish<<<128, 256, 0, stream>>>(T, rs2, rq2, rsH2, score, ctr + 1, hm1, 128);

    // layer 3 (no rs/rq: layer 4 has no hebbian)
    mfma_layer<128><<<dim3(1, 64), 256, 0, stream>>>(
        X2hl, B3, b3, mask2, T, X3hl, nullptr, nullptr, nullptr, 128, 64, 64, 64);
    hebb_finish<<<128, 256, 0, stream>>>(T, rs3, rq3, rsH3, score, ctr + 2, hm2, 64);

    // layer 4: out = relu(X3@W4^T+b4), N=1000 (B padded to 1024)
    mfma_layer<64><<<dim3(8, 64), 256, 0, stream>>>(
        X3hl, B4, b4, nullptr, nullptr, nullptr, out, nullptr, nullptr, 64, 0, 1024, 1000);
}

// Round 5
// 243.482 us; speedup vs baseline: 1.8359x; 1.0691x over previous
//
#include <hip/hip_runtime.h>
#include <math.h>

typedef __attribute__((ext_vector_type(8))) short short8;
typedef __attribute__((ext_vector_type(4))) float floatx4;

typedef __attribute__((address_space(1))) const unsigned int as1_uint;
typedef __attribute__((address_space(3))) unsigned int as3_uint;
#define GLD16(g, l) __builtin_amdgcn_global_load_lds((as1_uint*)(g), (as3_uint*)(l), 16, 0, 0)

__device__ __forceinline__ unsigned short f2bf(float f) {
    unsigned int u = __float_as_uint(f);
    return (unsigned short)((u + 0x7fffu + ((u >> 16) & 1u)) >> 16);
}
__device__ __forceinline__ float bf2f(unsigned short h) {
    return __uint_as_float(((unsigned int)h) << 16);
}

// ---------------------------------------------------------------------------
// convert_x: x[8192,1024] fp32 -> Axhl[8192,2048] bf16 ([hi|lo] per row).
// rs1/rq1 = rowsum/rowsumsq (exact fp32). Zeroes rs2/rq2/rs3/rq3, score, ctr.
// ---------------------------------------------------------------------------
__global__ __launch_bounds__(256) void convert_x(
    const float* __restrict__ x, unsigned short* __restrict__ Axhl,
    float* __restrict__ rs1, float* __restrict__ rq1,
    float* __restrict__ rs2, float* __restrict__ rq2,
    float* __restrict__ rs3, float* __restrict__ rq3,
    float* __restrict__ score, int* __restrict__ ctr)
{
    const int row = blockIdx.x, tid = threadIdx.x;
    if (row == 0) { score[tid] = 0.f; if (tid < 8) ctr[tid] = 0; }
    if (tid == 0) { rs2[row] = 0.f; rq2[row] = 0.f; rs3[row] = 0.f; rq3[row] = 0.f; }
    float4 v = *(const float4*)(x + (size_t)row * 1024 + (tid << 2));
    ushort4 h, l;
    h.x = f2bf(v.x); l.x = f2bf(v.x - bf2f(h.x));
    h.y = f2bf(v.y); l.y = f2bf(v.y - bf2f(h.y));
    h.z = f2bf(v.z); l.z = f2bf(v.z - bf2f(h.z));
    h.w = f2bf(v.w); l.w = f2bf(v.w - bf2f(h.w));
    *(ushort4*)(Axhl + (size_t)row * 2048 + (tid << 2)) = h;
    *(ushort4*)(Axhl + (size_t)row * 2048 + 1024 + (tid << 2)) = l;
    float s = v.x + v.y + v.z + v.w;
    float qq = v.x*v.x + v.y*v.y + v.z*v.z + v.w*v.w;
#pragma unroll
    for (int d = 1; d < 64; d <<= 1) { s += __shfl_xor(s, d, 64); qq += __shfl_xor(qq, d, 64); }
    __shared__ float sS[4], sQ[4];
    if ((tid & 63) == 0) { sS[tid >> 6] = s; sQ[tid >> 6] = qq; }
    __syncthreads();
    if (tid == 0) {
        rs1[row] = sS[0] + sS[1] + sS[2] + sS[3];
        rq1[row] = sQ[0] + sQ[1] + sQ[2] + sQ[3];
    }
}

// ---------------------------------------------------------------------------
// convert_w: all weights -> bf16 [hi|lo] packs; rowsums of H1/H2/H3.
// blocks: 0-255 H1, 256-511 W1, 512-639 H2, 640-767 W2, 768-831 H3,
//         832-895 W3, 896-1919 W4 (rows>=1000 zero-padded).
// ---------------------------------------------------------------------------
__global__ __launch_bounds__(256) void convert_w(
    const float* __restrict__ H1, const float* __restrict__ W1,
    const float* __restrict__ H2, const float* __restrict__ W2,
    const float* __restrict__ H3, const float* __restrict__ W3,
    const float* __restrict__ W4,
    unsigned short* __restrict__ B1, unsigned short* __restrict__ B2,
    unsigned short* __restrict__ B3, unsigned short* __restrict__ B4,
    float* __restrict__ rsH1, float* __restrict__ rsH2, float* __restrict__ rsH3)
{
    const int b = blockIdx.x, tid = threadIdx.x;
    const float* src; unsigned short* dst; int K; float* rsum = nullptr;
    if (b < 256)      { K = 1024; src = H1 + (size_t)b * 1024;        dst = B1 + (size_t)b * 2048;        rsum = rsH1 + b; }
    else if (b < 512) { K = 1024; src = W1 + (size_t)(b - 256) * 1024; dst = B1 + (size_t)b * 2048; }
    else if (b < 640) { K = 256;  src = H2 + (size_t)(b - 512) * 256;  dst = B2 + (size_t)(b - 512) * 512; rsum = rsH2 + (b - 512); }
    else if (b < 768) { K = 256;  src = W2 + (size_t)(b - 640) * 256;  dst = B2 + (size_t)(b - 512) * 512; }
    else if (b < 832) { K = 128;  src = H3 + (size_t)(b - 768) * 128;  dst = B3 + (size_t)(b - 768) * 256; rsum = rsH3 + (b - 768); }
    else if (b < 896) { K = 128;  src = W3 + (size_t)(b - 832) * 128;  dst = B3 + (size_t)(b - 768) * 256; }
    else { K = 64; int r = b - 896; src = (r < 1000) ? (W4 + (size_t)r * 64) : nullptr; dst = B4 + (size_t)r * 128; }

    float lsum = 0.f;
    if (tid * 4 < K) {
        float4 v = src ? *(const float4*)(src + tid * 4) : make_float4(0.f, 0.f, 0.f, 0.f);
        ushort4 h, l;
        h.x = f2bf(v.x); l.x = f2bf(v.x - bf2f(h.x));
        h.y = f2bf(v.y); l.y = f2bf(v.y - bf2f(h.y));
        h.z = f2bf(v.z); l.z = f2bf(v.z - bf2f(h.z));
        h.w = f2bf(v.w); l.w = f2bf(v.w - bf2f(h.w));
        *(ushort4*)(dst + tid * 4) = h;
        *(ushort4*)(dst + K + tid * 4) = l;
        lsum = v.x + v.y + v.z + v.w;
    }
    if (rsum) {
#pragma unroll
        for (int d = 1; d < 64; d <<= 1) lsum += __shfl_xor(lsum, d, 64);
        __shared__ float sS[4];
        if ((tid & 63) == 0) sS[tid >> 6] = lsum;
        __syncthreads();
        if (tid == 0) *rsum = sS[0] + sS[1] + sS[2] + sS[3];
    }
}

// ---------------------------------------------------------------------------
// mfma_layer: C[8192, Nh+Nw] = A @ B^T via 3-segment split-bf16
// (ah.bh + al.bh + ah.bl). A rows [hi(K)|lo(K)] bf16, stride 4K bytes.
// 128x128 tile, 4 waves (2x2), 4x4 of 16x16x32 mfma per wave, KW=64 k/iter,
// DOUBLE-buffered LDS (2 x 32 KB): one barrier/iter, prefetch(it+1) issued
// after the barrier overlaps compute(it) [r3-proven]; global_load_lds(16B)
// staging with XOR chunk swizzle (bank-conflict-free ds_read_b128, r4-proven
// 0 conflicts); XCD-aware block swizzle (A-slice per XCD, r4: FETCH 101->34MB).
// Epilogue: cols<Nh -> T fp32; else X=relu(+bias)*mask -> Xhl bf16 hi/lo +
// rs/rq row-reduction atomics; outF mode (L4): relu(+bias) -> fp32, ld NwReal.
// ---------------------------------------------------------------------------
#define KW 64
__global__ __launch_bounds__(256) void mfma_layer(
    const unsigned short* __restrict__ Ag, const unsigned short* __restrict__ Bg,
    const float* __restrict__ bias, const float* __restrict__ maskv,
    float* __restrict__ T, unsigned short* __restrict__ Xhl,
    float* __restrict__ outF,
    float* __restrict__ rs, float* __restrict__ rq,
    int K, int Nh, int Nw, int NwReal)
{
    constexpr int CPR = 8;               // 16-B chunks per 128-B LDS row
    constexpr int PERW = 4;              // staging instrs per wave per matrix
    constexpr int TILEB = 128 * 128;     // 16 KB per matrix tile
    __shared__ __align__(16) char lds[4 * TILEB];   // 2 bufs x (A | B)

    const int tid = threadIdx.x;
    const int w = tid >> 6, lane = tid & 63;
    const int q = lane >> 4, m16 = lane & 15;
    const int wm = w & 1, wn = w >> 1;

    // XCD swizzle: same-by blocks land on the same XCD (lin%8 heuristic)
    const int lin = blockIdx.y * gridDim.x + blockIdx.x;
    const int g = lin & 7, s = lin >> 3;
    const int by = g + ((s & 7) << 3);   // gridDim.y must be 64
    const int bx = s >> 3;

    const int strideB = 4 * K;           // bytes per [hi|lo] row
    const int u = lane & 7, v = lane >> 3;
    int aOff[PERW], bOff[PERW];
#pragma unroll
    for (int t0 = 0; t0 < PERW; ++t0) {
        const int t = w * PERW + t0;
        const int r = t * 8 + v;                  // row 0..127
        const int c = u ^ (r & 7);                // XOR chunk swizzle
        aOff[t0] = (by * 128 + r) * strideB + c * 16;
        bOff[t0] = (bx * 128 + r) * strideB + c * 16;
    }

    const char* Ab = (const char*)Ag;
    const char* Bb = (const char*)Bg;
    floatx4 acc[4][4] = {};

    const int kiters = K / KW;           // iters per segment
    const int NIT = 3 * kiters;

    auto stage = [&](int buf, int it) {
        const int seg = it / kiters;
        const int k0 = (it - seg * kiters) * KW;
        const int ka = ((seg == 1) ? 2 * K : 0) + 2 * k0;   // bytes
        const int kb = ((seg == 2) ? 2 * K : 0) + 2 * k0;
        char* base = lds + buf * 2 * TILEB;
#pragma unroll
        for (int t0 = 0; t0 < PERW; ++t0) {
            const int t = w * PERW + t0;
            GLD16(Ab + aOff[t0] + ka, base + t * 1024);
            GLD16(Bb + bOff[t0] + kb, base + TILEB + t * 1024);
        }
    };

    stage(0, 0);
    int cur = 0;
    for (int it = 0; it < NIT; ++it) {
        __syncthreads();                     // drains prefetch of buf[cur] +
                                             // prev iter's ds_reads of buf[cur^1]
        if (it + 1 < NIT) stage(cur ^ 1, it + 1);   // overlaps compute below
        const char* pb = lds + cur * 2 * TILEB;
#pragma unroll
        for (int h = 0; h < 2; ++h) {
            short8 af[4], bfr[4];
#pragma unroll
            for (int i = 0; i < 4; ++i) {
                const int ra = wm * 64 + i * 16 + m16;
                af[i] = *(const short8*)(pb + ra * 128 + (((h * 4 + q) ^ (ra & 7)) << 4));
                const int rb = wn * 64 + i * 16 + m16;
                bfr[i] = *(const short8*)(pb + TILEB + rb * 128 + (((h * 4 + q) ^ (rb & 7)) << 4));
            }
#pragma unroll
            for (int i = 0; i < 4; ++i)
#pragma unroll
                for (int j = 0; j < 4; ++j)
                    acc[i][j] = __builtin_amdgcn_mfma_f32_16x16x32_bf16(af[i], bfr[j], acc[i][j], 0, 0, 0);
        }
        cur ^= 1;
    }

    // epilogue; C/D layout: col = lane&15, row = q*4 + reg
    const int colW = bx * 128 + wn * 64;
    const bool isHwave = (outF == nullptr) && (colW < Nh);
#pragma unroll
    for (int i = 0; i < 4; ++i) {
        const int row0 = by * 128 + wm * 64 + i * 16 + q * 4;
        float rsum[4] = {0.f, 0.f, 0.f, 0.f}, rqsum[4] = {0.f, 0.f, 0.f, 0.f};
#pragma unroll
        for (int j = 0; j < 4; ++j) {
            const int col = colW + j * 16 + m16;
            floatx4 vv = acc[i][j];
            if (outF) {
                if (col < NwReal) {
                    const float bb = bias[col];
#pragma unroll
                    for (int rg = 0; rg < 4; ++rg)
                        outF[(size_t)(row0 + rg) * NwReal + col] = fmaxf(vv[rg] + bb, 0.f);
                }
            } else if (isHwave) {
#pragma unroll
                for (int rg = 0; rg < 4; ++rg)
                    T[(size_t)(row0 + rg) * Nh + col] = vv[rg];
            } else {
                const int c = col - Nh;
                const float bb = bias[c], mm = maskv[c];
#pragma unroll
                for (int rg = 0; rg < 4; ++rg) {
                    const float xv = fmaxf(vv[rg] + bb, 0.f) * mm;
                    const unsigned short hi = f2bf(xv);
                    const unsigned short lo = f2bf(xv - bf2f(hi));
                    Xhl[(size_t)(row0 + rg) * (2 * Nw) + c] = hi;
                    Xhl[(size_t)(row0 + rg) * (2 * Nw) + Nw + c] = lo;
                    rsum[rg] += xv; rqsum[rg] += xv * xv;
                }
            }
        }
        if (rs && !isHwave && !outF) {
#pragma unroll
            for (int rg = 0; rg < 4; ++rg) {
                float a_ = rsum[rg], b_ = rqsum[rg];
#pragma unroll
                for (int d = 1; d < 16; d <<= 1) {
                    a_ += __shfl_xor(a_, d, 64);
                    b_ += __shfl_xor(b_, d, 64);
                }
                if (m16 == 0) {
                    atomicAdd(&rs[row0 + rg], a_);
                    atomicAdd(&rq[row0 + rg], b_);
                }
            }
        }
    }
}

// ---------------------------------------------------------------------------
// hebb_finish: per block 64 rows of T: wgt = (rs/sqrt(rq))/||T_row||;
// score[y] += T[b,y]*wgt[b]; last block computes minmax mask -> hm and
// re-zeroes score for the next layer.
// ---------------------------------------------------------------------------
__global__ __launch_bounds__(256) void hebb_finish(
    const float* __restrict__ T, const float* __restrict__ rs,
    const float* __restrict__ rq, const float* __restrict__ rowsumH,
    float* __restrict__ score, int* __restrict__ counter,
    float* __restrict__ hm, int ysize)
{
    const int tid = threadIdx.x, lane = tid & 63, wave = tid >> 6;
    const int vecsz = ysize >> 6;
    const int b0 = blockIdx.x * 64;
    float accv[4] = {0.f, 0.f, 0.f, 0.f};
    for (int r = wave; r < 64; r += 4) {
        const float* Trow = T + (size_t)(b0 + r) * ysize;
        float vals[4] = {0.f, 0.f, 0.f, 0.f};
        if (vecsz == 4) { float4 t = *(const float4*)(Trow + (lane << 2)); vals[0]=t.x; vals[1]=t.y; vals[2]=t.z; vals[3]=t.w; }
        else if (vecsz == 2) { float2 t = *(const float2*)(Trow + (lane << 1)); vals[0]=t.x; vals[1]=t.y; }
        else vals[0] = Trow[lane];
        float sq = vals[0]*vals[0] + vals[1]*vals[1] + vals[2]*vals[2] + vals[3]*vals[3];
#pragma unroll
        for (int i = 1; i < 64; i <<= 1) sq += __shfl_xor(sq, i, 64);
        const float wgt = rs[b0 + r] / (sqrtf(rq[b0 + r]) * sqrtf(sq));
        for (int j = 0; j < 4; ++j) accv[j] += vals[j] * wgt;
    }
    __shared__ float sPart[4][256];
    for (int j = 0; j < vecsz; ++j) sPart[wave][lane * vecsz + j] = accv[j];
    __syncthreads();
    if (tid < ysize)
        atomicAdd(&score[tid], sPart[0][tid] + sPart[1][tid] + sPart[2][tid] + sPart[3][tid]);
    __syncthreads();
    __shared__ int lastFlag;
    if (tid == 0) {
        __threadfence();
        lastFlag = (atomicAdd(counter, 1) == (int)gridDim.x - 1) ? 1 : 0;
    }
    __syncthreads();
    if (!lastFlag) return;
    float full = 0.f;
    if (tid < ysize) {
        float sc = atomicAdd(&score[tid], 0.f);
        full = (1.f - 1.f / (float)ysize) * rowsumH[tid] + sc;
    }
    __shared__ float sMin[256], sMax[256];
    sMin[tid] = (tid < ysize) ? full : 3.4e38f;
    sMax[tid] = (tid < ysize) ? full : -3.4e38f;
    __syncthreads();
    for (int st = 128; st > 0; st >>= 1) {
        if (tid < st) { sMin[tid] = fminf(sMin[tid], sMin[tid+st]); sMax[tid] = fmaxf(sMax[tid], sMax[tid+st]); }
        __syncthreads();
    }
    if (tid < ysize) {
        float nrm = (full - sMin[0]) / (sMax[0] - sMin[0] + 1e-8f);
        hm[tid] = (nrm < 0.5f) ? 0.f : 1.f;
    }
    score[tid] = 0.f;   // ready for next layer
}

// ---------------------------------------------------------------------------
extern "C" void kernel_launch(void* const* d_in, const int* in_sizes, int n_in,
                              void* d_out, int out_size, void* d_ws, size_t ws_size,
                              hipStream_t stream)
{
    const float* x     = (const float*)d_in[0];
    const float* mask0 = (const float*)d_in[1];
    const float* mask1 = (const float*)d_in[2];
    const float* mask2 = (const float*)d_in[3];
    const float* W1 = (const float*)d_in[4];  const float* b1 = (const float*)d_in[5];
    const float* W2 = (const float*)d_in[6];  const float* b2 = (const float*)d_in[7];
    const float* W3 = (const float*)d_in[8];  const float* b3 = (const float*)d_in[9];
    const float* W4 = (const float*)d_in[10]; const float* b4 = (const float*)d_in[11];
    const float* H1 = (const float*)d_in[12];
    const float* H2 = (const float*)d_in[13];
    const float* H3 = (const float*)d_in[14];

    float* out = (float*)d_out;
    float* hm0 = out + (size_t)8192 * 1000;
    float* hm1 = hm0 + 256;
    float* hm2 = hm1 + 128;

    // ws layout (float units). Axhl (32 MB) dead after mfma L1 -> X2hl/X3hl alias it.
    float* ws = (float*)d_ws;
    unsigned short* Axhl = (unsigned short*)ws;                 // 8192*2048 bf16 (8388608 f)
    unsigned short* X2hl = (unsigned short*)ws;                 // alias: 8192*256 bf16
    unsigned short* X3hl = (unsigned short*)(ws + 1048576);     // alias: 8192*128 bf16
    float* p = ws + 8388608;
    unsigned short* B1 = (unsigned short*)p;  p += 524288;      // 512*2048
    unsigned short* B2 = (unsigned short*)p;  p += 65536;       // 256*512
    unsigned short* B3 = (unsigned short*)p;  p += 16384;       // 128*256
    unsigned short* B4 = (unsigned short*)p;  p += 65536;       // 1024*128
    float* T    = p;  p += 2097152;                             // 8192*256 fp32
    unsigned short* X1hl = (unsigned short*)p; p += 2097152;    // 8192*512 bf16
    float* rs1 = p; p += 8192;  float* rq1 = p; p += 8192;
    float* rs2 = p; p += 8192;  float* rq2 = p; p += 8192;
    float* rs3 = p; p += 8192;  float* rq3 = p; p += 8192;
    float* rsH1 = p; p += 256;  float* rsH2 = p; p += 128;  float* rsH3 = p; p += 64;
    float* score = p; p += 256;
    int* ctr = (int*)p;

    convert_x<<<8192, 256, 0, stream>>>(x, Axhl, rs1, rq1, rs2, rq2, rs3, rq3, score, ctr);
    convert_w<<<1920, 256, 0, stream>>>(H1, W1, H2, W2, H3, W3, W4, B1, B2, B3, B4, rsH1, rsH2, rsH3);

    // layer 1: T = x@H1^T, X1 = relu(x@W1^T+b1)*mask0 (+rs2/rq2)
    mfma_layer<<<dim3(4, 64), 256, 0, stream>>>(
        Axhl, B1, b1, mask0, T, X1hl, nullptr, rs2, rq2, 1024, 256, 256, 256);
    hebb_finish<<<128, 256, 0, stream>>>(T, rs1, rq1, rsH1, score, ctr + 0, hm0, 256);

    // layer 2
    mfma_layer<<<dim3(2, 64), 256, 0, stream>>>(
        X1hl, B2, b2, mask1, T, X2hl, nullptr, rs3, rq3, 256, 128, 128, 128);
    hebb_finish<<<128, 256, 0, stream>>>(T, rs2, rq2, rsH2, score, ctr + 1, hm1, 128);

    // layer 3 (no rs/rq: layer 4 has no hebbian)
    mfma_layer<<<dim3(1, 64), 256, 0, stream>>>(
        X2hl, B3, b3, mask2, T, X3hl, nullptr, nullptr, nullptr, 128, 64, 64, 64);
    hebb_finish<<<128, 256, 0, stream>>>(T, rs3, rq3, rsH3, score, ctr + 2, hm2, 64);

    // layer 4: out = relu(X3@W4^T+b4), N=1000 (B padded to 1024)
    mfma_layer<<<dim3(8, 64), 256, 0, stream>>>(
        X3hl, B4, b4, nullptr, nullptr, nullptr, out, nullptr, nullptr, 64, 0, 1024, 1000);
}

// Round 6
// 225.826 us; speedup vs baseline: 1.9794x; 1.0782x over previous
//
#include <hip/hip_runtime.h>
#include <math.h>

typedef __attribute__((ext_vector_type(8))) short short8;
typedef __attribute__((ext_vector_type(4))) float floatx4;

typedef __attribute__((address_space(1))) const unsigned int as1_uint;
typedef __attribute__((address_space(3))) unsigned int as3_uint;
#define GLD16(g, l) __builtin_amdgcn_global_load_lds((as1_uint*)(g), (as3_uint*)(l), 16, 0, 0)

__device__ __forceinline__ unsigned short f2bf(float f) {
    unsigned int u = __float_as_uint(f);
    return (unsigned short)((u + 0x7fffu + ((u >> 16) & 1u)) >> 16);
}
__device__ __forceinline__ float bf2f(unsigned short h) {
    return __uint_as_float(((unsigned int)h) << 16);
}

// ---------------------------------------------------------------------------
// convert_x: x[8192,1024] fp32 -> Axhl[8192,2048] bf16 ([hi|lo] per row).
// rs1/rq1 = rowsum/rowsumsq (exact fp32). Zeroes rs2/rq2/rs3/rq3, score, ctr.
// ---------------------------------------------------------------------------
__global__ __launch_bounds__(256) void convert_x(
    const float* __restrict__ x, unsigned short* __restrict__ Axhl,
    float* __restrict__ rs1, float* __restrict__ rq1,
    float* __restrict__ rs2, float* __restrict__ rq2,
    float* __restrict__ rs3, float* __restrict__ rq3,
    float* __restrict__ score, int* __restrict__ ctr)
{
    const int row = blockIdx.x, tid = threadIdx.x;
    if (row == 0) { score[tid] = 0.f; if (tid < 8) ctr[tid] = 0; }
    if (tid == 0) { rs2[row] = 0.f; rq2[row] = 0.f; rs3[row] = 0.f; rq3[row] = 0.f; }
    float4 v = *(const float4*)(x + (size_t)row * 1024 + (tid << 2));
    ushort4 h, l;
    h.x = f2bf(v.x); l.x = f2bf(v.x - bf2f(h.x));
    h.y = f2bf(v.y); l.y = f2bf(v.y - bf2f(h.y));
    h.z = f2bf(v.z); l.z = f2bf(v.z - bf2f(h.z));
    h.w = f2bf(v.w); l.w = f2bf(v.w - bf2f(h.w));
    *(ushort4*)(Axhl + (size_t)row * 2048 + (tid << 2)) = h;
    *(ushort4*)(Axhl + (size_t)row * 2048 + 1024 + (tid << 2)) = l;
    float s = v.x + v.y + v.z + v.w;
    float qq = v.x*v.x + v.y*v.y + v.z*v.z + v.w*v.w;
#pragma unroll
    for (int d = 1; d < 64; d <<= 1) { s += __shfl_xor(s, d, 64); qq += __shfl_xor(qq, d, 64); }
    __shared__ float sS[4], sQ[4];
    if ((tid & 63) == 0) { sS[tid >> 6] = s; sQ[tid >> 6] = qq; }
    __syncthreads();
    if (tid == 0) {
        rs1[row] = sS[0] + sS[1] + sS[2] + sS[3];
        rq1[row] = sQ[0] + sQ[1] + sQ[2] + sQ[3];
    }
}

// ---------------------------------------------------------------------------
// convert_w: all weights -> bf16 [hi|lo] packs; rowsums of H1/H2/H3.
// blocks: 0-255 H1, 256-511 W1, 512-639 H2, 640-767 W2, 768-831 H3,
//         832-895 W3, 896-1919 W4 (rows>=1000 zero-padded).
// ---------------------------------------------------------------------------
__global__ __launch_bounds__(256) void convert_w(
    const float* __restrict__ H1, const float* __restrict__ W1,
    const float* __restrict__ H2, const float* __restrict__ W2,
    const float* __restrict__ H3, const float* __restrict__ W3,
    const float* __restrict__ W4,
    unsigned short* __restrict__ B1, unsigned short* __restrict__ B2,
    unsigned short* __restrict__ B3, unsigned short* __restrict__ B4,
    float* __restrict__ rsH1, float* __restrict__ rsH2, float* __restrict__ rsH3)
{
    const int b = blockIdx.x, tid = threadIdx.x;
    const float* src; unsigned short* dst; int K; float* rsum = nullptr;
    if (b < 256)      { K = 1024; src = H1 + (size_t)b * 1024;        dst = B1 + (size_t)b * 2048;        rsum = rsH1 + b; }
    else if (b < 512) { K = 1024; src = W1 + (size_t)(b - 256) * 1024; dst = B1 + (size_t)b * 2048; }
    else if (b < 640) { K = 256;  src = H2 + (size_t)(b - 512) * 256;  dst = B2 + (size_t)(b - 512) * 512; rsum = rsH2 + (b - 512); }
    else if (b < 768) { K = 256;  src = W2 + (size_t)(b - 640) * 256;  dst = B2 + (size_t)(b - 512) * 512; }
    else if (b < 832) { K = 128;  src = H3 + (size_t)(b - 768) * 128;  dst = B3 + (size_t)(b - 768) * 256; rsum = rsH3 + (b - 768); }
    else if (b < 896) { K = 128;  src = W3 + (size_t)(b - 832) * 128;  dst = B3 + (size_t)(b - 768) * 256; }
    else { K = 64; int r = b - 896; src = (r < 1000) ? (W4 + (size_t)r * 64) : nullptr; dst = B4 + (size_t)r * 128; }

    float lsum = 0.f;
    if (tid * 4 < K) {
        float4 v = src ? *(const float4*)(src + tid * 4) : make_float4(0.f, 0.f, 0.f, 0.f);
        ushort4 h, l;
        h.x = f2bf(v.x); l.x = f2bf(v.x - bf2f(h.x));
        h.y = f2bf(v.y); l.y = f2bf(v.y - bf2f(h.y));
        h.z = f2bf(v.z); l.z = f2bf(v.z - bf2f(h.z));
        h.w = f2bf(v.w); l.w = f2bf(v.w - bf2f(h.w));
        *(ushort4*)(dst + tid * 4) = h;
        *(ushort4*)(dst + K + tid * 4) = l;
        lsum = v.x + v.y + v.z + v.w;
    }
    if (rsum) {
#pragma unroll
        for (int d = 1; d < 64; d <<= 1) lsum += __shfl_xor(lsum, d, 64);
        __shared__ float sS[4];
        if ((tid & 63) == 0) sS[tid >> 6] = lsum;
        __syncthreads();
        if (tid == 0) *rsum = sS[0] + sS[1] + sS[2] + sS[3];
    }
}

// ---------------------------------------------------------------------------
// mfma_layer<TM,TN>: C[8192, Nh+Nw] = A @ B^T, split-bf16 3-product
// (ah.bh + al.bh + ah.bl), SEGMENT-INTERLEAVED: each 32-k chunk stages
// {A-hi, A-lo, B-hi, B-lo} once and issues all 3 mfma products -> 3x MFMA
// per barrier vs r5, and A-hi read once. TMxTN tile, 4 waves (2x2),
// double-buffered LDS, global_load_lds(16B) staging, XOR chunk swizzle
// (0 bank conflicts, r4-proven), XCD swizzle (r4: FETCH 101->34MB).
// Tiles sized so grid >= 2 blocks/CU (r5 lesson: 1 block/CU exposes the
// vmcnt(0)-before-barrier drain; only co-resident blocks hide it).
// Epilogue: cols<Nh -> T fp32; else X=relu(+bias)*mask -> Xhl bf16 hi/lo +
// rs/rq row atomics; outF mode (L4): relu(+bias) -> fp32, width NwReal.
// ---------------------------------------------------------------------------
template<int TM, int TN>
__global__ __launch_bounds__(256) void mfma_layer(
    const unsigned short* __restrict__ Ag, const unsigned short* __restrict__ Bg,
    const float* __restrict__ bias, const float* __restrict__ maskv,
    float* __restrict__ T, unsigned short* __restrict__ Xhl,
    float* __restrict__ outF,
    float* __restrict__ rs, float* __restrict__ rq,
    int K, int Nh, int Nw, int NwReal)
{
    constexpr int MI = TM / 32;          // mfma row-tiles per wave
    constexpr int NJ = TN / 32;          // mfma col-tiles per wave
    constexpr int IA = TM / 16;          // 1024-B staging instrs per A section
    constexpr int IB = TN / 16;
    constexpr int NI = 2 * (IA + IB);    // instrs per buffer
    constexpr int PERW = NI / 4;
    constexpr int BUFB = NI * 1024;      // bytes per buffer
    __shared__ __align__(16) char lds[2 * BUFB];

    const int tid = threadIdx.x;
    const int w = tid >> 6, lane = tid & 63;
    const int q = lane >> 4, m16 = lane & 15;
    const int wm = w & 1, wn = w >> 1;

    // XCD swizzle: all bx-tiles of a given by land on one XCD (A-tile L2 reuse)
    const int lin = blockIdx.y * gridDim.x + blockIdx.x;
    const int g = lin & 7, idx = lin >> 3;
    const int rows8 = gridDim.y >> 3;    // gridDim.y must be a multiple of 8
    const int by = g + 8 * (idx % rows8);
    const int bx = idx / rows8;

    const int strideB = 4 * K;           // bytes per [hi|lo] row
    const int v = lane >> 2, u = lane & 3;   // staging: 16 rows x 4 chunks/instr

    // per-staging-instr source pointers (swizzled chunk), +2*k0 at stage time
    const char* srcp[PERW];
#pragma unroll
    for (int t0 = 0; t0 < PERW; ++t0) {
        const int t = w * PERW + t0;
        int rloc; const char* base;
        if (t < IA)               { rloc = t * 16 + v;                base = (const char*)Ag + (size_t)(by * TM + rloc) * strideB; }
        else if (t < 2 * IA)      { rloc = (t - IA) * 16 + v;         base = (const char*)Ag + (size_t)(by * TM + rloc) * strideB + 2 * K; }
        else if (t < 2 * IA + IB) { rloc = (t - 2 * IA) * 16 + v;     base = (const char*)Bg + (size_t)(bx * TN + rloc) * strideB; }
        else                      { rloc = (t - 2 * IA - IB) * 16 + v; base = (const char*)Bg + (size_t)(bx * TN + rloc) * strideB + 2 * K; }
        srcp[t0] = base + ((u ^ (rloc & 3)) << 4);
    }

    auto stage = [&](int buf, int k0) {
        char* dst = lds + buf * BUFB + (w * PERW) * 1024;
        const int kb = 2 * k0;
#pragma unroll
        for (int t0 = 0; t0 < PERW; ++t0)
            GLD16(srcp[t0] + kb, dst + t0 * 1024);
    };

    floatx4 acc[MI][NJ] = {};
    const int NIT = K / 32;

    stage(0, 0);
    int cur = 0;
    for (int it = 0; it < NIT; ++it) {
        __syncthreads();                       // drain staging of buf[cur]
        if (it + 1 < NIT) stage(cur ^ 1, (it + 1) * 32);   // overlaps compute
        const char* pb = lds + cur * BUFB;
        short8 ah[MI], al[MI], bh[NJ], bl[NJ];
#pragma unroll
        for (int i = 0; i < MI; ++i) {
            const int ra = wm * (TM / 2) + i * 16 + m16;
            const int so = (q ^ (ra & 3)) << 4;
            ah[i] = *(const short8*)(pb + ra * 64 + so);
            al[i] = *(const short8*)(pb + IA * 1024 + ra * 64 + so);
        }
#pragma unroll
        for (int j = 0; j < NJ; ++j) {
            const int rb = wn * (TN / 2) + j * 16 + m16;
            const int so = (q ^ (rb & 3)) << 4;
            bh[j] = *(const short8*)(pb + 2 * IA * 1024 + rb * 64 + so);
            bl[j] = *(const short8*)(pb + (2 * IA + IB) * 1024 + rb * 64 + so);
        }
#pragma unroll
        for (int i = 0; i < MI; ++i)
#pragma unroll
            for (int j = 0; j < NJ; ++j) {
                acc[i][j] = __builtin_amdgcn_mfma_f32_16x16x32_bf16(ah[i], bh[j], acc[i][j], 0, 0, 0);
                acc[i][j] = __builtin_amdgcn_mfma_f32_16x16x32_bf16(al[i], bh[j], acc[i][j], 0, 0, 0);
                acc[i][j] = __builtin_amdgcn_mfma_f32_16x16x32_bf16(ah[i], bl[j], acc[i][j], 0, 0, 0);
            }
        cur ^= 1;
    }

    // epilogue; C/D layout: col = lane&15, row = q*4 + reg  [m89-verified]
    const int colW = bx * TN + wn * (TN / 2);
    const bool isHwave = (outF == nullptr) && (colW < Nh);
#pragma unroll
    for (int i = 0; i < MI; ++i) {
        const int row0 = by * TM + wm * (TM / 2) + i * 16 + q * 4;
        float rsum[4] = {0.f, 0.f, 0.f, 0.f}, rqsum[4] = {0.f, 0.f, 0.f, 0.f};
#pragma unroll
        for (int j = 0; j < NJ; ++j) {
            const int col = colW + j * 16 + m16;
            floatx4 vv = acc[i][j];
            if (outF) {
                if (col < NwReal) {
                    const float bb = bias[col];
#pragma unroll
                    for (int rg = 0; rg < 4; ++rg)
                        outF[(size_t)(row0 + rg) * NwReal + col] = fmaxf(vv[rg] + bb, 0.f);
                }
            } else if (isHwave) {
#pragma unroll
                for (int rg = 0; rg < 4; ++rg)
                    T[(size_t)(row0 + rg) * Nh + col] = vv[rg];
            } else {
                const int c = col - Nh;
                const float bb = bias[c], mm = maskv[c];
#pragma unroll
                for (int rg = 0; rg < 4; ++rg) {
                    const float xv = fmaxf(vv[rg] + bb, 0.f) * mm;
                    const unsigned short hi = f2bf(xv);
                    const unsigned short lo = f2bf(xv - bf2f(hi));
                    Xhl[(size_t)(row0 + rg) * (2 * Nw) + c] = hi;
                    Xhl[(size_t)(row0 + rg) * (2 * Nw) + Nw + c] = lo;
                    rsum[rg] += xv; rqsum[rg] += xv * xv;
                }
            }
        }
        if (rs && !isHwave && !outF) {
#pragma unroll
            for (int rg = 0; rg < 4; ++rg) {
                float a_ = rsum[rg], b_ = rqsum[rg];
#pragma unroll
                for (int d = 1; d < 16; d <<= 1) {
                    a_ += __shfl_xor(a_, d, 64);
                    b_ += __shfl_xor(b_, d, 64);
                }
                if (m16 == 0) {
                    atomicAdd(&rs[row0 + rg], a_);
                    atomicAdd(&rq[row0 + rg], b_);
                }
            }
        }
    }
}

// ---------------------------------------------------------------------------
// hebb_finish: per block 64 rows of T: wgt = (rs/sqrt(rq))/||T_row||;
// score[y] += T[b,y]*wgt[b]; last block computes minmax mask -> hm and
// re-zeroes score for the next layer.
// ---------------------------------------------------------------------------
__global__ __launch_bounds__(256) void hebb_finish(
    const float* __restrict__ T, const float* __restrict__ rs,
    const float* __restrict__ rq, const float* __restrict__ rowsumH,
    float* __restrict__ score, int* __restrict__ counter,
    float* __restrict__ hm, int ysize)
{
    const int tid = threadIdx.x, lane = tid & 63, wave = tid >> 6;
    const int vecsz = ysize >> 6;
    const int b0 = blockIdx.x * 64;
    float accv[4] = {0.f, 0.f, 0.f, 0.f};
    for (int r = wave; r < 64; r += 4) {
        const float* Trow = T + (size_t)(b0 + r) * ysize;
        float vals[4] = {0.f, 0.f, 0.f, 0.f};
        if (vecsz == 4) { float4 t = *(const float4*)(Trow + (lane << 2)); vals[0]=t.x; vals[1]=t.y; vals[2]=t.z; vals[3]=t.w; }
        else if (vecsz == 2) { float2 t = *(const float2*)(Trow + (lane << 1)); vals[0]=t.x; vals[1]=t.y; }
        else vals[0] = Trow[lane];
        float sq = vals[0]*vals[0] + vals[1]*vals[1] + vals[2]*vals[2] + vals[3]*vals[3];
#pragma unroll
        for (int i = 1; i < 64; i <<= 1) sq += __shfl_xor(sq, i, 64);
        const float wgt = rs[b0 + r] / (sqrtf(rq[b0 + r]) * sqrtf(sq));
        for (int j = 0; j < 4; ++j) accv[j] += vals[j] * wgt;
    }
    __shared__ float sPart[4][256];
    for (int j = 0; j < vecsz; ++j) sPart[wave][lane * vecsz + j] = accv[j];
    __syncthreads();
    if (tid < ysize)
        atomicAdd(&score[tid], sPart[0][tid] + sPart[1][tid] + sPart[2][tid] + sPart[3][tid]);
    __syncthreads();
    __shared__ int lastFlag;
    if (tid == 0) {
        __threadfence();
        lastFlag = (atomicAdd(counter, 1) == (int)gridDim.x - 1) ? 1 : 0;
    }
    __syncthreads();
    if (!lastFlag) return;
    float full = 0.f;
    if (tid < ysize) {
        float sc = atomicAdd(&score[tid], 0.f);
        full = (1.f - 1.f / (float)ysize) * rowsumH[tid] + sc;
    }
    __shared__ float sMin[256], sMax[256];
    sMin[tid] = (tid < ysize) ? full : 3.4e38f;
    sMax[tid] = (tid < ysize) ? full : -3.4e38f;
    __syncthreads();
    for (int st = 128; st > 0; st >>= 1) {
        if (tid < st) { sMin[tid] = fminf(sMin[tid], sMin[tid+st]); sMax[tid] = fmaxf(sMax[tid], sMax[tid+st]); }
        __syncthreads();
    }
    if (tid < ysize) {
        float nrm = (full - sMin[0]) / (sMax[0] - sMin[0] + 1e-8f);
        hm[tid] = (nrm < 0.5f) ? 0.f : 1.f;
    }
    score[tid] = 0.f;   // ready for next layer
}

// ---------------------------------------------------------------------------
extern "C" void kernel_launch(void* const* d_in, const int* in_sizes, int n_in,
                              void* d_out, int out_size, void* d_ws, size_t ws_size,
                              hipStream_t stream)
{
    const float* x     = (const float*)d_in[0];
    const float* mask0 = (const float*)d_in[1];
    const float* mask1 = (const float*)d_in[2];
    const float* mask2 = (const float*)d_in[3];
    const float* W1 = (const float*)d_in[4];  const float* b1 = (const float*)d_in[5];
    const float* W2 = (const float*)d_in[6];  const float* b2 = (const float*)d_in[7];
    const float* W3 = (const float*)d_in[8];  const float* b3 = (const float*)d_in[9];
    const float* W4 = (const float*)d_in[10]; const float* b4 = (const float*)d_in[11];
    const float* H1 = (const float*)d_in[12];
    const float* H2 = (const float*)d_in[13];
    const float* H3 = (const float*)d_in[14];

    float* out = (float*)d_out;
    float* hm0 = out + (size_t)8192 * 1000;
    float* hm1 = hm0 + 256;
    float* hm2 = hm1 + 128;

    // ws layout (float units). Axhl (32 MB) dead after mfma L1 -> X2hl/X3hl alias it.
    float* ws = (float*)d_ws;
    unsigned short* Axhl = (unsigned short*)ws;                 // 8192*2048 bf16 (8388608 f)
    unsigned short* X2hl = (unsigned short*)ws;                 // alias: 8192*256 bf16
    unsigned short* X3hl = (unsigned short*)(ws + 1048576);     // alias: 8192*128 bf16
    float* p = ws + 8388608;
    unsigned short* B1 = (unsigned short*)p;  p += 524288;      // 512*2048
    unsigned short* B2 = (unsigned short*)p;  p += 65536;       // 256*512
    unsigned short* B3 = (unsigned short*)p;  p += 16384;       // 128*256
    unsigned short* B4 = (unsigned short*)p;  p += 65536;       // 1024*128
    float* T    = p;  p += 2097152;                             // 8192*256 fp32
    unsigned short* X1hl = (unsigned short*)p; p += 2097152;    // 8192*512 bf16
    float* rs1 = p; p += 8192;  float* rq1 = p; p += 8192;
    float* rs2 = p; p += 8192;  float* rq2 = p; p += 8192;
    float* rs3 = p; p += 8192;  float* rq3 = p; p += 8192;
    float* rsH1 = p; p += 256;  float* rsH2 = p; p += 128;  float* rsH3 = p; p += 64;
    float* score = p; p += 256;
    int* ctr = (int*)p;

    convert_x<<<8192, 256, 0, stream>>>(x, Axhl, rs1, rq1, rs2, rq2, rs3, rq3, score, ctr);
    convert_w<<<1920, 256, 0, stream>>>(H1, W1, H2, W2, H3, W3, W4, B1, B2, B3, B4, rsH1, rsH2, rsH3);

    // layer 1: T = x@H1^T, X1 = relu(x@W1^T+b1)*mask0 (+rs2/rq2)  [512 blocks]
    mfma_layer<128, 64><<<dim3(8, 64), 256, 0, stream>>>(
        Axhl, B1, b1, mask0, T, X1hl, nullptr, rs2, rq2, 1024, 256, 256, 256);
    hebb_finish<<<128, 256, 0, stream>>>(T, rs1, rq1, rsH1, score, ctr + 0, hm0, 256);

    // layer 2  [512 blocks]
    mfma_layer<64, 64><<<dim3(4, 128), 256, 0, stream>>>(
        X1hl, B2, b2, mask1, T, X2hl, nullptr, rs3, rq3, 256, 128, 128, 128);
    hebb_finish<<<128, 256, 0, stream>>>(T, rs2, rq2, rsH2, score, ctr + 1, hm1, 128);

    // layer 3 (no rs/rq: layer 4 has no hebbian)  [256 blocks]
    mfma_layer<64, 64><<<dim3(2, 128), 256, 0, stream>>>(
        X2hl, B3, b3, mask2, T, X3hl, nullptr, nullptr, nullptr, 128, 64, 64, 64);
    hebb_finish<<<128, 256, 0, stream>>>(T, rs3, rq3, rsH3, score, ctr + 2, hm2, 64);

    // layer 4: out = relu(X3@W4^T+b4), N=1000 (B padded to 1024)  [1024 blocks]
    mfma_layer<128, 64><<<dim3(16, 64), 256, 0, stream>>>(
        X3hl, B4, b4, nullptr, nullptr, nullptr, out, nullptr, nullptr, 64, 0, 1024, 1000);
}

// Round 7
// 205.623 us; speedup vs baseline: 2.1739x; 1.0983x over previous
//
#include <hip/hip_runtime.h>
#include <math.h>

typedef __attribute__((ext_vector_type(8))) short short8;
typedef __attribute__((ext_vector_type(4))) float floatx4;

typedef __attribute__((address_space(1))) const unsigned int as1_uint;
typedef __attribute__((address_space(3))) unsigned int as3_uint;
#define GLD16(g, l) __builtin_amdgcn_global_load_lds((as1_uint*)(g), (as3_uint*)(l), 16, 0, 0)

__device__ __forceinline__ unsigned short f2bf(float f) {
    unsigned int u = __float_as_uint(f);
    return (unsigned short)((u + 0x7fffu + ((u >> 16) & 1u)) >> 16);
}
__device__ __forceinline__ float bf2f(unsigned short h) {
    return __uint_as_float(((unsigned int)h) << 16);
}

// ---------------------------------------------------------------------------
// convert_all: blocks [0,8192): x rows -> Axhl bf16 [hi|lo] + rs1/rq1 + zero
// accumulators. blocks [8192,10112): weights -> B1..B4 bf16 [hi|lo] + rowsums.
// ---------------------------------------------------------------------------
__global__ __launch_bounds__(256) void convert_all(
    const float* __restrict__ x, unsigned short* __restrict__ Axhl,
    const float* __restrict__ H1, const float* __restrict__ W1,
    const float* __restrict__ H2, const float* __restrict__ W2,
    const float* __restrict__ H3, const float* __restrict__ W3,
    const float* __restrict__ W4,
    unsigned short* __restrict__ B1, unsigned short* __restrict__ B2,
    unsigned short* __restrict__ B3, unsigned short* __restrict__ B4,
    float* __restrict__ rs1, float* __restrict__ rq1,
    float* __restrict__ rs2, float* __restrict__ rq2,
    float* __restrict__ rs3, float* __restrict__ rq3,
    float* __restrict__ rsH1, float* __restrict__ rsH2, float* __restrict__ rsH3,
    float* __restrict__ score1, float* __restrict__ score2,
    float* __restrict__ score3, int* __restrict__ ctr)
{
    const int b = blockIdx.x, tid = threadIdx.x;
    if (b < 8192) {
        if (b == 0) {
            score1[tid] = 0.f; score2[tid] = 0.f; score3[tid] = 0.f;
            if (tid < 8) ctr[tid] = 0;
        }
        if (tid == 0) { rs2[b] = 0.f; rq2[b] = 0.f; rs3[b] = 0.f; rq3[b] = 0.f; }
        float4 v = *(const float4*)(x + (size_t)b * 1024 + (tid << 2));
        ushort4 h, l;
        h.x = f2bf(v.x); l.x = f2bf(v.x - bf2f(h.x));
        h.y = f2bf(v.y); l.y = f2bf(v.y - bf2f(h.y));
        h.z = f2bf(v.z); l.z = f2bf(v.z - bf2f(h.z));
        h.w = f2bf(v.w); l.w = f2bf(v.w - bf2f(h.w));
        *(ushort4*)(Axhl + (size_t)b * 2048 + (tid << 2)) = h;
        *(ushort4*)(Axhl + (size_t)b * 2048 + 1024 + (tid << 2)) = l;
        float s = v.x + v.y + v.z + v.w;
        float qq = v.x*v.x + v.y*v.y + v.z*v.z + v.w*v.w;
#pragma unroll
        for (int d = 1; d < 64; d <<= 1) { s += __shfl_xor(s, d, 64); qq += __shfl_xor(qq, d, 64); }
        __shared__ float sS[4], sQ[4];
        if ((tid & 63) == 0) { sS[tid >> 6] = s; sQ[tid >> 6] = qq; }
        __syncthreads();
        if (tid == 0) {
            rs1[b] = sS[0] + sS[1] + sS[2] + sS[3];
            rq1[b] = sQ[0] + sQ[1] + sQ[2] + sQ[3];
        }
    } else {
        const int wb = b - 8192;
        const float* src; unsigned short* dst; int K; float* rsum = nullptr;
        if (wb < 256)      { K = 1024; src = H1 + (size_t)wb * 1024;         dst = B1 + (size_t)wb * 2048;        rsum = rsH1 + wb; }
        else if (wb < 512) { K = 1024; src = W1 + (size_t)(wb - 256) * 1024; dst = B1 + (size_t)wb * 2048; }
        else if (wb < 640) { K = 256;  src = H2 + (size_t)(wb - 512) * 256;  dst = B2 + (size_t)(wb - 512) * 512; rsum = rsH2 + (wb - 512); }
        else if (wb < 768) { K = 256;  src = W2 + (size_t)(wb - 640) * 256;  dst = B2 + (size_t)(wb - 512) * 512; }
        else if (wb < 832) { K = 128;  src = H3 + (size_t)(wb - 768) * 128;  dst = B3 + (size_t)(wb - 768) * 256; rsum = rsH3 + (wb - 768); }
        else if (wb < 896) { K = 128;  src = W3 + (size_t)(wb - 832) * 128;  dst = B3 + (size_t)(wb - 768) * 256; }
        else { K = 64; int r = wb - 896; src = (r < 1000) ? (W4 + (size_t)r * 64) : nullptr; dst = B4 + (size_t)r * 128; }
        float lsum = 0.f;
        if (tid * 4 < K) {
            float4 v = src ? *(const float4*)(src + tid * 4) : make_float4(0.f, 0.f, 0.f, 0.f);
            ushort4 h, l;
            h.x = f2bf(v.x); l.x = f2bf(v.x - bf2f(h.x));
            h.y = f2bf(v.y); l.y = f2bf(v.y - bf2f(h.y));
            h.z = f2bf(v.z); l.z = f2bf(v.z - bf2f(h.z));
            h.w = f2bf(v.w); l.w = f2bf(v.w - bf2f(h.w));
            *(ushort4*)(dst + tid * 4) = h;
            *(ushort4*)(dst + K + tid * 4) = l;
            lsum = v.x + v.y + v.z + v.w;
        }
        if (rsum) {
#pragma unroll
            for (int d = 1; d < 64; d <<= 1) lsum += __shfl_xor(lsum, d, 64);
            __shared__ float sW[4];
            if ((tid & 63) == 0) sW[tid >> 6] = lsum;
            __syncthreads();
            if (tid == 0) *rsum = sW[0] + sW[1] + sW[2] + sW[3];
        }
    }
}

// ---------------------------------------------------------------------------
// hebb_dev: one block, 64 rows of T (prev layer): wgt=(rs/sqrt(rq))/||T_row||;
// score[y] += T[b,y]*wgt[b]; last arriving block does minmax -> hm.
// Shared memory overlaid onto caller's LDS buffer (needs ~6.2 KB).
// ---------------------------------------------------------------------------
__device__ void hebb_dev(char* smem, int hb,
    const float* __restrict__ T, const float* __restrict__ rs,
    const float* __restrict__ rq, const float* __restrict__ rowsumH,
    float* __restrict__ score, int* __restrict__ counter,
    float* __restrict__ hm, int ysize, int nHebb)
{
    float* sPart = (float*)smem;                 // 4*256
    float* sMin  = sPart + 1024;                 // 256
    float* sMax  = sMin + 256;                   // 256
    int*   lastFlag = (int*)(sMax + 256);
    const int tid = threadIdx.x, lane = tid & 63, wave = tid >> 6;
    const int vecsz = ysize >> 6;
    const int b0 = hb * 64;
    float accv[4] = {0.f, 0.f, 0.f, 0.f};
    for (int r = wave; r < 64; r += 4) {
        const float* Trow = T + (size_t)(b0 + r) * ysize;
        float vals[4] = {0.f, 0.f, 0.f, 0.f};
        if (vecsz == 4)      { float4 t = *(const float4*)(Trow + (lane << 2)); vals[0]=t.x; vals[1]=t.y; vals[2]=t.z; vals[3]=t.w; }
        else if (vecsz == 2) { float2 t = *(const float2*)(Trow + (lane << 1)); vals[0]=t.x; vals[1]=t.y; }
        else                 vals[0] = Trow[lane];
        float sq = vals[0]*vals[0] + vals[1]*vals[1] + vals[2]*vals[2] + vals[3]*vals[3];
#pragma unroll
        for (int i = 1; i < 64; i <<= 1) sq += __shfl_xor(sq, i, 64);
        const float wgt = rs[b0 + r] / (sqrtf(rq[b0 + r]) * sqrtf(sq));
        for (int j = 0; j < 4; ++j) accv[j] += vals[j] * wgt;
    }
    for (int j = 0; j < vecsz; ++j) sPart[wave * 256 + lane * vecsz + j] = accv[j];
    __syncthreads();
    if (tid < ysize)
        atomicAdd(&score[tid], sPart[tid] + sPart[256 + tid] + sPart[512 + tid] + sPart[768 + tid]);
    __syncthreads();
    if (tid == 0) {
        __threadfence();
        *lastFlag = (atomicAdd(counter, 1) == nHebb - 1) ? 1 : 0;
    }
    __syncthreads();
    if (!*lastFlag) return;
    float full = 0.f;
    if (tid < ysize) {
        float sc = atomicAdd(&score[tid], 0.f);
        full = (1.f - 1.f / (float)ysize) * rowsumH[tid] + sc;
    }
    sMin[tid] = (tid < ysize) ? full : 3.4e38f;
    sMax[tid] = (tid < ysize) ? full : -3.4e38f;
    __syncthreads();
    for (int st = 128; st > 0; st >>= 1) {
        if (tid < st) { sMin[tid] = fminf(sMin[tid], sMin[tid+st]); sMax[tid] = fmaxf(sMax[tid], sMax[tid+st]); }
        __syncthreads();
    }
    if (tid < ysize) {
        float nrm = (full - sMin[0]) / (sMax[0] - sMin[0] + 1e-8f);
        hm[tid] = (nrm < 0.5f) ? 0.f : 1.f;
    }
}

// ---------------------------------------------------------------------------
// mfma_hebb<TM,TN>: blocks [0,nHebb) run hebb_dev on the PREVIOUS layer's T
// (overlapped under this layer's GEMM); blocks [nHebb, nHebb+gx*gy) compute
// C[8192, Nh+Nw] = A @ B^T via interleaved split-bf16 (ah.bh+al.bh+ah.bl),
// double-buffered LDS, GLD16 staging, XOR chunk swizzle (r>>1)&3 — 2-way max
// (free; r6's r&3 caused 4-way = 3.1M conflicts), XCD-aware block swizzle.
// ---------------------------------------------------------------------------
template<int TM, int TN>
__global__ __launch_bounds__(256) void mfma_hebb(
    const unsigned short* __restrict__ Ag, const unsigned short* __restrict__ Bg,
    const float* __restrict__ bias, const float* __restrict__ maskv,
    float* __restrict__ T, unsigned short* __restrict__ Xhl,
    float* __restrict__ outF,
    float* __restrict__ rs, float* __restrict__ rq,
    int K, int Nh, int Nw, int NwReal, int ryShift,
    const float* __restrict__ hT, const float* __restrict__ hrs,
    const float* __restrict__ hrq, const float* __restrict__ hrsH,
    float* __restrict__ hscore, int* __restrict__ hctr,
    float* __restrict__ hhm, int hy, int nHebb)
{
    constexpr int MI = TM / 32;
    constexpr int NJ = TN / 32;
    constexpr int IA = TM / 16;
    constexpr int IB = TN / 16;
    constexpr int NI = 2 * (IA + IB);
    constexpr int PERW = NI / 4;
    constexpr int BUFB = NI * 1024;
    __shared__ __align__(16) char lds[2 * BUFB];

    if ((int)blockIdx.x < nHebb) {
        hebb_dev(lds, blockIdx.x, hT, hrs, hrq, hrsH, hscore, hctr, hhm, hy, nHebb);
        return;
    }

    const int tid = threadIdx.x;
    const int w = tid >> 6, lane = tid & 63;
    const int q = lane >> 4, m16 = lane & 15;
    const int wm = w & 1, wn = w >> 1;

    const int lin = blockIdx.x - nHebb;
    const int g = lin & 7, idx = lin >> 3;
    const int by = g + 8 * (idx & ((1 << ryShift) - 1));
    const int bx = idx >> ryShift;

    const int strideB = 4 * K;
    const int v = lane >> 2, u = lane & 3;

    const char* srcp[PERW];
#pragma unroll
    for (int t0 = 0; t0 < PERW; ++t0) {
        const int t = w * PERW + t0;
        int rloc; const char* base;
        if (t < IA)               { rloc = t * 16 + v;                 base = (const char*)Ag + (size_t)(by * TM + rloc) * strideB; }
        else if (t < 2 * IA)      { rloc = (t - IA) * 16 + v;          base = (const char*)Ag + (size_t)(by * TM + rloc) * strideB + 2 * K; }
        else if (t < 2 * IA + IB) { rloc = (t - 2 * IA) * 16 + v;      base = (const char*)Bg + (size_t)(bx * TN + rloc) * strideB; }
        else                      { rloc = (t - 2 * IA - IB) * 16 + v; base = (const char*)Bg + (size_t)(bx * TN + rloc) * strideB + 2 * K; }
        srcp[t0] = base + ((u ^ ((rloc >> 1) & 3)) << 4);   // 2-way max swizzle
    }

    auto stage = [&](int buf, int k0) {
        char* dst = lds + buf * BUFB + (w * PERW) * 1024;
        const int kb = 2 * k0;
#pragma unroll
        for (int t0 = 0; t0 < PERW; ++t0)
            GLD16(srcp[t0] + kb, dst + t0 * 1024);
    };

    floatx4 acc[MI][NJ] = {};
    const int NIT = K / 32;

    stage(0, 0);
    int cur = 0;
    for (int it = 0; it < NIT; ++it) {
        __syncthreads();
        if (it + 1 < NIT) stage(cur ^ 1, (it + 1) * 32);
        const char* pb = lds + cur * BUFB;
        short8 ah[MI], al[MI], bh[NJ], bl[NJ];
#pragma unroll
        for (int i = 0; i < MI; ++i) {
            const int ra = wm * (TM / 2) + i * 16 + m16;
            const int so = ((q ^ ((ra >> 1) & 3)) << 4);
            ah[i] = *(const short8*)(pb + ra * 64 + so);
            al[i] = *(const short8*)(pb + IA * 1024 + ra * 64 + so);
        }
#pragma unroll
        for (int j = 0; j < NJ; ++j) {
            const int rb = wn * (TN / 2) + j * 16 + m16;
            const int so = ((q ^ ((rb >> 1) & 3)) << 4);
            bh[j] = *(const short8*)(pb + 2 * IA * 1024 + rb * 64 + so);
            bl[j] = *(const short8*)(pb + (2 * IA + IB) * 1024 + rb * 64 + so);
        }
#pragma unroll
        for (int i = 0; i < MI; ++i)
#pragma unroll
            for (int j = 0; j < NJ; ++j) {
                acc[i][j] = __builtin_amdgcn_mfma_f32_16x16x32_bf16(ah[i], bh[j], acc[i][j], 0, 0, 0);
                acc[i][j] = __builtin_amdgcn_mfma_f32_16x16x32_bf16(al[i], bh[j], acc[i][j], 0, 0, 0);
                acc[i][j] = __builtin_amdgcn_mfma_f32_16x16x32_bf16(ah[i], bl[j], acc[i][j], 0, 0, 0);
            }
        cur ^= 1;
    }

    // epilogue; C/D layout: col = lane&15, row = q*4 + reg  [m89-verified]
    const int colW = bx * TN + wn * (TN / 2);
    const bool isHwave = (outF == nullptr) && (colW < Nh);
#pragma unroll
    for (int i = 0; i < MI; ++i) {
        const int row0 = by * TM + wm * (TM / 2) + i * 16 + q * 4;
        float rsum[4] = {0.f, 0.f, 0.f, 0.f}, rqsum[4] = {0.f, 0.f, 0.f, 0.f};
#pragma unroll
        for (int j = 0; j < NJ; ++j) {
            const int col = colW + j * 16 + m16;
            floatx4 vv = acc[i][j];
            if (outF) {
                if (col < NwReal) {
                    const float bb = bias[col];
#pragma unroll
                    for (int rg = 0; rg < 4; ++rg)
                        outF[(size_t)(row0 + rg) * NwReal + col] = fmaxf(vv[rg] + bb, 0.f);
                }
            } else if (isHwave) {
#pragma unroll
                for (int rg = 0; rg < 4; ++rg)
                    T[(size_t)(row0 + rg) * Nh + col] = vv[rg];
            } else {
                const int c = col - Nh;
                const float bb = bias[c], mm = maskv[c];
#pragma unroll
                for (int rg = 0; rg < 4; ++rg) {
                    const float xv = fmaxf(vv[rg] + bb, 0.f) * mm;
                    const unsigned short hi = f2bf(xv);
                    const unsigned short lo = f2bf(xv - bf2f(hi));
                    Xhl[(size_t)(row0 + rg) * (2 * Nw) + c] = hi;
                    Xhl[(size_t)(row0 + rg) * (2 * Nw) + Nw + c] = lo;
                    rsum[rg] += xv; rqsum[rg] += xv * xv;
                }
            }
        }
        if (rs && !isHwave && !outF) {
#pragma unroll
            for (int rg = 0; rg < 4; ++rg) {
                float a_ = rsum[rg], b_ = rqsum[rg];
#pragma unroll
                for (int d = 1; d < 16; d <<= 1) {
                    a_ += __shfl_xor(a_, d, 64);
                    b_ += __shfl_xor(b_, d, 64);
                }
                if (m16 == 0) {
                    atomicAdd(&rs[row0 + rg], a_);
                    atomicAdd(&rq[row0 + rg], b_);
                }
            }
        }
    }
}

// ---------------------------------------------------------------------------
extern "C" void kernel_launch(void* const* d_in, const int* in_sizes, int n_in,
                              void* d_out, int out_size, void* d_ws, size_t ws_size,
                              hipStream_t stream)
{
    const float* x     = (const float*)d_in[0];
    const float* mask0 = (const float*)d_in[1];
    const float* mask1 = (const float*)d_in[2];
    const float* mask2 = (const float*)d_in[3];
    const float* W1 = (const float*)d_in[4];  const float* b1 = (const float*)d_in[5];
    const float* W2 = (const float*)d_in[6];  const float* b2 = (const float*)d_in[7];
    const float* W3 = (const float*)d_in[8];  const float* b3 = (const float*)d_in[9];
    const float* W4 = (const float*)d_in[10]; const float* b4 = (const float*)d_in[11];
    const float* H1 = (const float*)d_in[12];
    const float* H2 = (const float*)d_in[13];
    const float* H3 = (const float*)d_in[14];

    float* out = (float*)d_out;
    float* hm0 = out + (size_t)8192 * 1000;
    float* hm1 = hm0 + 256;
    float* hm2 = hm1 + 128;

    // ws layout (float units). Axhl (32 MB) dead after L1 -> X2hl/X3hl alias it.
    float* ws = (float*)d_ws;
    unsigned short* Axhl = (unsigned short*)ws;               // 8192*2048 bf16
    unsigned short* X2hl = (unsigned short*)ws;               // alias: 8192*512 shorts
    unsigned short* X3hl = (unsigned short*)(ws + 1048576);   // alias: 8192*256 shorts
    float* p = ws + 8388608;
    unsigned short* B1 = (unsigned short*)p;  p += 524288;    // 512*2048
    unsigned short* B2 = (unsigned short*)p;  p += 65536;     // 256*512
    unsigned short* B3 = (unsigned short*)p;  p += 16384;     // 128*256
    unsigned short* B4 = (unsigned short*)p;  p += 65536;     // 1024*128
    float* T1 = p; p += 2097152;                              // 8192*256 fp32
    float* T2 = p; p += 1048576;                              // 8192*128 fp32
    float* T3 = p; p += 524288;                               // 8192*64  fp32
    unsigned short* X1hl = (unsigned short*)p; p += 2097152;  // 8192*512 bf16 hl
    float* rs1 = p; p += 8192;  float* rq1 = p; p += 8192;
    float* rs2 = p; p += 8192;  float* rq2 = p; p += 8192;
    float* rs3 = p; p += 8192;  float* rq3 = p; p += 8192;
    float* rsH1 = p; p += 256;  float* rsH2 = p; p += 128;  float* rsH3 = p; p += 64;
    float* score1 = p; p += 256;
    float* score2 = p; p += 256;
    float* score3 = p; p += 256;
    int* ctr = (int*)p;

    convert_all<<<10112, 256, 0, stream>>>(
        x, Axhl, H1, W1, H2, W2, H3, W3, W4, B1, B2, B3, B4,
        rs1, rq1, rs2, rq2, rs3, rq3, rsH1, rsH2, rsH3,
        score1, score2, score3, ctr);

    // L1: T1 = x@H1^T, X1 = relu(x@W1^T+b1)*mask0 (+rs2/rq2). 512 gemm blocks.
    mfma_hebb<128, 64><<<512, 256, 0, stream>>>(
        Axhl, B1, b1, mask0, T1, X1hl, nullptr, rs2, rq2,
        1024, 256, 256, 256, /*ryShift=*/3,
        nullptr, nullptr, nullptr, nullptr, nullptr, nullptr, nullptr, 0, 0);

    // L2 (+hebb of layer1): 128 hebb + 512 gemm blocks.
    mfma_hebb<64, 64><<<640, 256, 0, stream>>>(
        X1hl, B2, b2, mask1, T2, X2hl, nullptr, rs3, rq3,
        256, 128, 128, 128, /*ryShift=*/4,
        T1, rs1, rq1, rsH1, score1, ctr + 0, hm0, 256, 128);

    // L3 (+hebb of layer2): 128 hebb + 256 gemm blocks.
    mfma_hebb<64, 64><<<384, 256, 0, stream>>>(
        X2hl, B3, b3, mask2, T3, X3hl, nullptr, nullptr, nullptr,
        128, 64, 64, 64, /*ryShift=*/4,
        T2, rs2, rq2, rsH2, score2, ctr + 1, hm1, 128, 128);

    // L4 (+hebb of layer3): out = relu(X3@W4^T+b4), N=1000 (B padded 1024).
    // 128 hebb + 1024 gemm blocks.
    mfma_hebb<128, 64><<<1152, 256, 0, stream>>>(
        X3hl, B4, b4, nullptr, nullptr, nullptr, out, nullptr, nullptr,
        64, 0, 1024, 1000, /*ryShift=*/3,
        T3, rs3, rq3, rsH3, score3, ctr + 2, hm2, 64, 128);
}